// Round 9
// baseline (467.862 us; speedup 1.0000x reference)
//
#include <hip/hip_runtime.h>
#include <cfloat>

#define BB   32
#define VV   2048
#define KNB  40
#define FIN  64
#define DD   4
#define PP   64
#define NN   (BB*VV)           // 65536

static __device__ __forceinline__ float fast_tanh(float z) {
    z = fminf(fmaxf(z, -15.f), 15.f);
    float e = __expf(2.f * z);
    return (e - 1.f) / (e + 1.f);
}

static __device__ __forceinline__ float rfl_f(float x) {
    return __uint_as_float(
        (unsigned)__builtin_amdgcn_readfirstlane(__float_as_int(x)));
}

// Wave64 inclusive add-scan via DPP (rocPRIM pattern): 6 VALU ops, no DS pipe.
static __device__ __forceinline__ int wave_incl_scan(int x) {
    x += __builtin_amdgcn_update_dpp(0, x, 0x111, 0xf, 0xf, true); // row_shr:1
    x += __builtin_amdgcn_update_dpp(0, x, 0x112, 0xf, 0xf, true); // row_shr:2
    x += __builtin_amdgcn_update_dpp(0, x, 0x114, 0xf, 0xf, true); // row_shr:4
    x += __builtin_amdgcn_update_dpp(0, x, 0x118, 0xf, 0xf, true); // row_shr:8
    x += __builtin_amdgcn_update_dpp(0, x, 0x142, 0xa, 0xf, true); // row_bcast:15 -> rows 1,3
    x += __builtin_amdgcn_update_dpp(0, x, 0x143, 0xc, 0xf, true); // row_bcast:31 -> rows 2,3
    return x;
}

// ---------------------------------------------------------------------------
// Kernel 1: coords = x@W_s + b_s (N x 4), feats = x@W_f + b_f (N x 64)
// (unchanged, passing)
// ---------------------------------------------------------------------------
__global__ __launch_bounds__(256) void k_embed(
    const float* __restrict__ x, const float* __restrict__ Ws,
    const float* __restrict__ bs, const float* __restrict__ Wf,
    const float* __restrict__ bf, float* __restrict__ coords,
    float* __restrict__ feats)
{
    __shared__ float Xs[64][68];
    __shared__ float Wfs[64][64];
    __shared__ float Wss[64][4];
    const int tid  = threadIdx.x;
    const int row0 = blockIdx.x * 64;

    #pragma unroll
    for (int i = 0; i < 4; ++i) {
        const int idx = tid + i * 256;
        const int r   = idx >> 4;
        const int k4  = (idx & 15) << 2;
        float4 v = *(const float4*)(x + (size_t)(row0 + r) * FIN + k4);
        Xs[k4+0][r] = v.x; Xs[k4+1][r] = v.y; Xs[k4+2][r] = v.z; Xs[k4+3][r] = v.w;
        ((float4*)Wfs)[idx] = ((const float4*)Wf)[idx];
    }
    if (tid < 64) *(float4*)Wss[tid] = ((const float4*)Ws)[tid];
    __syncthreads();

    const int tx = tid & 15;
    const int ty = tid >> 4;
    float acc[4][4] = {};
    #pragma unroll 16
    for (int k = 0; k < 64; ++k) {
        float4 a = *(const float4*)&Xs[k][ty * 4];
        float4 b = *(const float4*)&Wfs[k][tx * 4];
        acc[0][0] += a.x*b.x; acc[0][1] += a.x*b.y; acc[0][2] += a.x*b.z; acc[0][3] += a.x*b.w;
        acc[1][0] += a.y*b.x; acc[1][1] += a.y*b.y; acc[1][2] += a.y*b.z; acc[1][3] += a.y*b.w;
        acc[2][0] += a.z*b.x; acc[2][1] += a.z*b.y; acc[2][2] += a.z*b.z; acc[2][3] += a.z*b.w;
        acc[3][0] += a.w*b.x; acc[3][1] += a.w*b.y; acc[3][2] += a.w*b.z; acc[3][3] += a.w*b.w;
    }
    const float4 bfv = *(const float4*)(bf + tx * 4);
    const float ar[4] = {bfv.x, bfv.y, bfv.z, bfv.w};
    #pragma unroll
    for (int i = 0; i < 4; ++i) {
        float4 o = { acc[i][0] + ar[0], acc[i][1] + ar[1],
                     acc[i][2] + ar[2], acc[i][3] + ar[3] };
        *(float4*)(feats + (size_t)(row0 + ty * 4 + i) * PP + tx * 4) = o;
    }

    const int cr = tid >> 2, cc = tid & 3;
    float ca = bs[cc];
    #pragma unroll 16
    for (int k = 0; k < 64; ++k) ca += Xs[k][cr] * Wss[k][cc];
    coords[(size_t)(row0 + cr) * DD + cc] = ca;
}

// ---------------------------------------------------------------------------
// select_collect: given packed 8-bit bins (4/u32), nearmask (bit j: candidate
// was histogrammed), and the filled per-wave histogram, find the rank-40
// boundary and scatter the selected indices to cp[0..KNB).
// EXACTLY equivalent to the float-compare select of R4-R6 (passing):
//   bin < g1         <=>  d2 < g1/scale  (exact pow2 scale)
//   bin == g1 & near <=>  d2 in boundary bin (far/self have near=0).
// Returns false (before collecting) if total < KNB and allow_fail.
// ---------------------------------------------------------------------------
static __device__ __forceinline__ bool select_collect(
    const unsigned int (&bp)[8], const unsigned int nearmask,
    int* __restrict__ hw, int* __restrict__ cp, const int lane,
    const bool allow_fail)
{
    int4 hv = ((const int4*)hw)[lane];
    const int local = hv.x + hv.y + hv.z + hv.w;
    const int incl  = wave_incl_scan(local);
    if (allow_fail) {
        const int total = __builtin_amdgcn_readlane(incl, 63);
        if (total < KNB) return false;
    }
    const int excl = incl - local;
    const bool pred = (excl < KNB) && (incl >= KNB);
    const unsigned long long m = __ballot(pred);
    const int src = (m == 0ull) ? 0 : ((int)__ffsll(m) - 1);  // uniform
    int gg = 0, nnb = 0;
    if (pred) {
        const int hh[4] = {hv.x, hv.y, hv.z, hv.w};
        int cacc = excl, found = -1;
        #pragma unroll
        for (int q = 0; q < 4; ++q) {
            if (found < 0 && cacc + hh[q] >= KNB) { found = q; nnb = cacc; }
            cacc += hh[q];
        }
        gg = (lane << 2) + found;
    }
    const int g1  = __builtin_amdgcn_readlane(gg,  src);
    const int nb1 = __builtin_amdgcn_readlane(nnb, src);

    // ---- masks from bin bytes (bfe + cmp; no floats) ----
    unsigned int maskA = 0u, maskB = 0u;
    #pragma unroll
    for (int j = 0; j < 32; ++j) {
        const int bb = (int)((bp[j >> 2] >> ((j & 3) * 8)) & 255u);
        if (bb < g1) maskA |= (1u << j);
        else if (bb == g1) maskB |= (1u << j);
    }
    maskB &= nearmask;                     // drop far/self sentinels (bin 255)

    const int packed = __popc(maskA) | (__popc(maskB) << 16);
    const int incl2  = wave_incl_scan(packed);
    const int excl2  = incl2 - packed;
    int baseA = excl2 & 0xFFFF;            // region A: [0, nb1)
    int baseB = nb1 + (excl2 >> 16);       // region B: [nb1, 40), capped
    #pragma unroll
    for (int j = 0; j < 32; ++j) {
        const bool a = (maskA >> j) & 1u;
        const bool b = (maskB >> j) & 1u;
        const int  dst = a ? baseA : baseB;
        if ((a | b) && (a || baseB < KNB))
            cp[dst] = lane + (j << 6);
        baseA += (int)a;
        baseB += (int)b;
    }
    return true;
}

// rebuild_fb: rare fallback — re-derive d2, bins at [0,1024) width 4, re-hist.
static __device__ __forceinline__ void rebuild_fb(
    const float4* __restrict__ cb4, const float cvx, const float cvy,
    const float cvz, const float cvw, const int jself,
    const int lself, int* __restrict__ hw, unsigned int (&bp)[8],
    unsigned int& nearm, const int lane)
{
    const int4 izero = {0, 0, 0, 0};
    ((int4*)hw)[lane] = izero;
    nearm = 0u;
    #pragma unroll
    for (int q = 0; q < 8; ++q) bp[q] = 0u;
    #pragma unroll
    for (int j = 0; j < 32; ++j) {
        const float4 cw = cb4[lane + (j << 6)];
        const float dx = cvx - cw.x, dy = cvy - cw.y;
        const float dz = cvz - cw.z, dw = cvw - cw.w;
        float d2 = dx*dx + dy*dy + dz*dz + dw*dw;
        if (j == jself && lane == lself) d2 = FLT_MAX;
        const bool nr = (d2 < 1024.f);
        const int  bb = nr ? (int)(d2 * 0.25f) : 255;
        bp[j >> 2] |= (unsigned int)bb << ((j & 3) * 8);
        nearm      |= (nr ? 1u : 0u) << j;
        if (nr) atomicAdd(&hw[bb], 1);
    }
}

// ---------------------------------------------------------------------------
// Kernel 2a: k_select — top-40 KNN selection, ONE row per wave, bin-packed.
// R9: occupancy ladder is now fully calibrated — 4-wave tier (VGPR>64) =
// 21%/193-251us; 8-wave tier w/ 20MB spill (R6) = 42%/162us; 8-wave tier w/
// 641MB spill (R8) = 80% resident but HBM-bound on spill. Never tried:
// <=64 VGPR with ZERO spill. The 2-row live set can't fit; 1-row bin-packed
// state (bp[8]+near+scalarized cv+load batch ~45 regs) can. (256,8) pins
// the tier; the no-spill signature to verify: WRITE_SIZE ~10.2MB.
// Select semantics identical to passing R4-R8. Output: 40 u32 idx per row.
// ---------------------------------------------------------------------------
__global__ __launch_bounds__(256, 8) void k_select(
    const float* __restrict__ coords, float* __restrict__ collected)
{
    __shared__ int hist[4][256];       // 4 KB (per-wave)
    __shared__ int candP[4][KNB];      // 640 B: neighbor idx

    const int tid   = threadIdx.x;
    const int lane  = tid & 63;
    const int w     = tid >> 6;
    // XCD swizzle: 16384 blocks, 8 XCDs -> 2048 contiguous blocks per XCD.
    const int bid   = (int)blockIdx.x;
    const int swz   = ((bid & 7) << 11) + (bid >> 3);
    // one row per wave (wave-uniform)
    const int vu    = __builtin_amdgcn_readfirstlane((swz << 2) + w);
    const int batch = vu >> 11;
    const int vloc  = vu & (VV - 1);
    const float4* cb4 = (const float4*)(coords + (size_t)batch * VV * DD);

    const int4 izero = {0, 0, 0, 0};

    // query coords -> SGPRs (uniform)
    const float4 cvv = cb4[vloc];
    const float cvx = rfl_f(cvv.x), cvy = rfl_f(cvv.y);
    const float cvz = rfl_f(cvv.z), cvw = rfl_f(cvv.w);
    const int jself = vloc >> 6;
    const int lself = vloc & 63;

    ((int4*)hist[w])[lane] = izero;

    // ---- fused distance + bin-pack + histogram ----
    unsigned int bp[8] = {0,0,0,0,0,0,0,0};
    unsigned int nearm = 0u;
    #pragma unroll
    for (int j = 0; j < 32; ++j) {
        const float4 cw = cb4[lane + (j << 6)];
        const float dx = cvx - cw.x, dy = cvy - cw.y;
        const float dz = cvz - cw.z, dw = cvw - cw.w;
        float d2 = dx*dx + dy*dy + dz*dz + dw*dw;
        if (j == jself && lane == lself) d2 = FLT_MAX;  // self -> sentinel
        const bool nr = (d2 < 4.f);
        const int  bb = nr ? (int)(d2 * 64.f) : 255;
        bp[j >> 2] |= (unsigned int)bb << ((j & 3) * 8);
        nearm      |= (nr ? 1u : 0u) << j;
        if (nr) atomicAdd(&hist[w][bb], 1);
    }

    // ---- select + collect (fallback rare, wave-uniform) ----
    if (!select_collect(bp, nearm, hist[w], candP[w], lane, true)) {
        rebuild_fb(cb4, cvx, cvy, cvz, cvw, jself, lself,
                   hist[w], bp, nearm, lane);
        select_collect(bp, nearm, hist[w], candP[w], lane, false);
    }

    // ---- lanes 0..39: coalesced idx write to the row slot ----
    if (lane < KNB) {
        const unsigned int u0 = (unsigned int)candP[w][lane];
        ((unsigned int*)(collected + ((size_t)vu << 7)))[lane] = u0;
    }
}

// ---------------------------------------------------------------------------
// Kernel 2b: k_pool — gather 40 neighbor feature rows, weighted max/mean.
// (unchanged from R7/R8, passing): weight exp(-10*d2) recomputed here from
// coords (full fp32), readlane -> SGPR idx/weight, saddr gathers, row slot
// overwritten with pooled output.
// ---------------------------------------------------------------------------
__global__ __launch_bounds__(256) void k_pool(
    const float* __restrict__ coords, const float* __restrict__ feats,
    float* __restrict__ collected)
{
    const int tid  = threadIdx.x;
    const int lane = tid & 63;
    const int w4   = tid >> 6;             // wave in block: 0..3
    // XCD swizzle: 16384 blocks, 8 XCDs -> 2048 contiguous blocks per XCD.
    const int bid  = (int)blockIdx.x;
    const int swz  = ((bid & 7) << 11) + (bid >> 3);
    const int v    = (swz << 2) + w4;      // global row
    const int batch = v >> 11;
    const float*  fb  = feats + (size_t)batch * VV * PP;
    const float4* cb4 = (const float4*)(coords + (size_t)batch * VV * DD);
    float* rowp = collected + ((size_t)v << 7);

    // packed candidates + per-lane weight (lanes 0..39), before overwrite
    unsigned int u = 0u; float wgt = 0.f;
    if (lane < KNB) {
        u = ((const unsigned int*)rowp)[lane];
        const float4 cv = cb4[v & (VV - 1)];
        const float4 cw = cb4[u];
        const float dx = cv.x - cw.x, dy = cv.y - cw.y;
        const float dz = cv.z - cw.z, dw = cv.w - cw.w;
        wgt = __expf(-10.f * (dx*dx + dy*dy + dz*dz + dw*dw));
    }

    float mx = -FLT_MAX, sm = 0.f;
    #pragma unroll
    for (int j0 = 0; j0 < KNB; j0 += 20) {
        float fv[20]; float wv[20];
        #pragma unroll
        for (int t = 0; t < 20; ++t) {
            const int si = __builtin_amdgcn_readlane((int)u, j0 + t);   // SGPR
            wv[t] = __uint_as_float(
                (unsigned int)__builtin_amdgcn_readlane(__float_as_int(wgt), j0 + t));
            fv[t] = fb[(size_t)(si * PP) + lane];                       // saddr
        }
        #pragma unroll
        for (int t = 0; t < 20; ++t) {
            const float nv = fv[t] * wv[t];
            mx = fmaxf(mx, nv);
            sm += nv;
        }
    }
    rowp[lane]      = mx;
    rowp[PP + lane] = sm * (1.f / KNB);
}

// ---------------------------------------------------------------------------
// Kernel 3: out = tanh(concat(x, collected) @ W_out + b_out), (N x 192)@(192 x 128)
// (unchanged, passing)
// ---------------------------------------------------------------------------
__global__ __launch_bounds__(256) void k_out(
    const float* __restrict__ x, const float* __restrict__ collected,
    const float* __restrict__ Wout, const float* __restrict__ bout,
    float* __restrict__ out)
{
    __shared__ float As[16][68];   // [kk][r], +4 pad
    __shared__ float Bs[16][128];
    const int tid = threadIdx.x;
    const int tx  = tid & 15;
    const int ty  = tid >> 4;
    const int row0 = blockIdx.x * 64;

    float acc[4][8];
    #pragma unroll
    for (int i = 0; i < 4; ++i)
        #pragma unroll
        for (int j = 0; j < 8; ++j) acc[i][j] = 0.f;

    for (int k0 = 0; k0 < 192; k0 += 16) {
        {   // stage A tile transposed: thread loads (r, kk4..kk4+3), scatters
            const int r   = tid >> 2;
            const int kk4 = (tid & 3) << 2;
            const float* src = (k0 < 64)
                ? (x + (size_t)(row0 + r) * FIN + (k0 + kk4))
                : (collected + (size_t)(row0 + r) * 128 + (k0 - 64 + kk4));
            float4 v = *(const float4*)src;
            As[kk4+0][r] = v.x; As[kk4+1][r] = v.y;
            As[kk4+2][r] = v.z; As[kk4+3][r] = v.w;
        }
        #pragma unroll
        for (int rep = 0; rep < 2; ++rep) {
            const int e = (tid + rep * 256) * 4;
            const int kk = e >> 7, c = e & 127;
            *(float4*)&Bs[kk][c] = *(const float4*)(Wout + (size_t)(k0 + kk) * 128 + c);
        }
        __syncthreads();
        #pragma unroll
        for (int kk = 0; kk < 16; ++kk) {
            float4 a  = *(const float4*)&As[kk][ty * 4];
            float4 b0 = *(const float4*)&Bs[kk][tx * 4];
            float4 b1 = *(const float4*)&Bs[kk][64 + tx * 4];
            const float av[4] = {a.x, a.y, a.z, a.w};
            #pragma unroll
            for (int i = 0; i < 4; ++i) {
                acc[i][0] += av[i] * b0.x; acc[i][1] += av[i] * b0.y;
                acc[i][2] += av[i] * b0.z; acc[i][3] += av[i] * b0.w;
                acc[i][4] += av[i] * b1.x; acc[i][5] += av[i] * b1.y;
                acc[i][6] += av[i] * b1.z; acc[i][7] += av[i] * b1.w;
            }
        }
        __syncthreads();
    }

    #pragma unroll
    for (int i = 0; i < 4; ++i) {
        const int row = row0 + ty * 4 + i;
        float4 o0, o1;
        o0.x = fast_tanh(acc[i][0] + bout[tx*4+0]);
        o0.y = fast_tanh(acc[i][1] + bout[tx*4+1]);
        o0.z = fast_tanh(acc[i][2] + bout[tx*4+2]);
        o0.w = fast_tanh(acc[i][3] + bout[tx*4+3]);
        o1.x = fast_tanh(acc[i][4] + bout[64+tx*4+0]);
        o1.y = fast_tanh(acc[i][5] + bout[64+tx*4+1]);
        o1.z = fast_tanh(acc[i][6] + bout[64+tx*4+2]);
        o1.w = fast_tanh(acc[i][7] + bout[64+tx*4+3]);
        *(float4*)(out + (size_t)row * 128 + tx * 4)      = o0;
        *(float4*)(out + (size_t)row * 128 + 64 + tx * 4) = o1;
    }
}

// ---------------------------------------------------------------------------
extern "C" void kernel_launch(void* const* d_in, const int* in_sizes, int n_in,
                              void* d_out, int out_size, void* d_ws, size_t ws_size,
                              hipStream_t stream)
{
    const float* x    = (const float*)d_in[0];
    // d_in[1] = row_splits: uniform arange(B+1)*V — fixed structure, unused.
    const float* Ws   = (const float*)d_in[2];
    const float* bs   = (const float*)d_in[3];
    const float* Wf   = (const float*)d_in[4];
    const float* bf   = (const float*)d_in[5];
    const float* Wout = (const float*)d_in[6];
    const float* bout = (const float*)d_in[7];
    float* out = (float*)d_out;

    float* coords = (float*)d_ws;                                            // 1 MB
    float* feats  = (float*)((char*)d_ws + (size_t)NN * DD * sizeof(float)); // 16 MB
    float* collected = out;   // reuse d_out as scratch for pooled features

    hipLaunchKernelGGL(k_embed, dim3(NN / 64), dim3(256), 0, stream,
                       x, Ws, bs, Wf, bf, coords, feats);
    // selection: 1 row per wave, 4 waves/block -> 16384 blocks
    hipLaunchKernelGGL(k_select, dim3(NN / 4), dim3(256), 0, stream,
                       coords, collected);
    // pooling: 1 row per wave, 4 waves/block -> 16384 blocks
    hipLaunchKernelGGL(k_pool, dim3(NN / 4), dim3(256), 0, stream,
                       coords, feats, collected);
    hipLaunchKernelGGL(k_out, dim3(NN / 64), dim3(256), 0, stream,
                       x, collected, Wout, bout, out);
}

// Round 10
// 371.660 us; speedup vs baseline: 1.2588x; 1.2588x over previous
//
#include <hip/hip_runtime.h>
#include <cfloat>

#define BB   32
#define VV   2048
#define KNB  40
#define FIN  64
#define DD   4
#define PP   64
#define NN   (BB*VV)           // 65536

static __device__ __forceinline__ float fast_tanh(float z) {
    z = fminf(fmaxf(z, -15.f), 15.f);
    float e = __expf(2.f * z);
    return (e - 1.f) / (e + 1.f);
}

static __device__ __forceinline__ float rfl_f(float x) {
    return __uint_as_float(
        (unsigned)__builtin_amdgcn_readfirstlane(__float_as_int(x)));
}

// Wave64 inclusive add-scan via DPP (rocPRIM pattern): 6 VALU ops, no DS pipe.
static __device__ __forceinline__ int wave_incl_scan(int x) {
    x += __builtin_amdgcn_update_dpp(0, x, 0x111, 0xf, 0xf, true); // row_shr:1
    x += __builtin_amdgcn_update_dpp(0, x, 0x112, 0xf, 0xf, true); // row_shr:2
    x += __builtin_amdgcn_update_dpp(0, x, 0x114, 0xf, 0xf, true); // row_shr:4
    x += __builtin_amdgcn_update_dpp(0, x, 0x118, 0xf, 0xf, true); // row_shr:8
    x += __builtin_amdgcn_update_dpp(0, x, 0x142, 0xa, 0xf, true); // row_bcast:15 -> rows 1,3
    x += __builtin_amdgcn_update_dpp(0, x, 0x143, 0xc, 0xf, true); // row_bcast:31 -> rows 2,3
    return x;
}

// ---------------------------------------------------------------------------
// Kernel 1: coords = x@W_s + b_s (N x 4), feats = x@W_f + b_f (N x 64)
// (unchanged, passing)
// ---------------------------------------------------------------------------
__global__ __launch_bounds__(256) void k_embed(
    const float* __restrict__ x, const float* __restrict__ Ws,
    const float* __restrict__ bs, const float* __restrict__ Wf,
    const float* __restrict__ bf, float* __restrict__ coords,
    float* __restrict__ feats)
{
    __shared__ float Xs[64][68];
    __shared__ float Wfs[64][64];
    __shared__ float Wss[64][4];
    const int tid  = threadIdx.x;
    const int row0 = blockIdx.x * 64;

    #pragma unroll
    for (int i = 0; i < 4; ++i) {
        const int idx = tid + i * 256;
        const int r   = idx >> 4;
        const int k4  = (idx & 15) << 2;
        float4 v = *(const float4*)(x + (size_t)(row0 + r) * FIN + k4);
        Xs[k4+0][r] = v.x; Xs[k4+1][r] = v.y; Xs[k4+2][r] = v.z; Xs[k4+3][r] = v.w;
        ((float4*)Wfs)[idx] = ((const float4*)Wf)[idx];
    }
    if (tid < 64) *(float4*)Wss[tid] = ((const float4*)Ws)[tid];
    __syncthreads();

    const int tx = tid & 15;
    const int ty = tid >> 4;
    float acc[4][4] = {};
    #pragma unroll 16
    for (int k = 0; k < 64; ++k) {
        float4 a = *(const float4*)&Xs[k][ty * 4];
        float4 b = *(const float4*)&Wfs[k][tx * 4];
        acc[0][0] += a.x*b.x; acc[0][1] += a.x*b.y; acc[0][2] += a.x*b.z; acc[0][3] += a.x*b.w;
        acc[1][0] += a.y*b.x; acc[1][1] += a.y*b.y; acc[1][2] += a.y*b.z; acc[1][3] += a.y*b.w;
        acc[2][0] += a.z*b.x; acc[2][1] += a.z*b.y; acc[2][2] += a.z*b.z; acc[2][3] += a.z*b.w;
        acc[3][0] += a.w*b.x; acc[3][1] += a.w*b.y; acc[3][2] += a.w*b.z; acc[3][3] += a.w*b.w;
    }
    const float4 bfv = *(const float4*)(bf + tx * 4);
    const float ar[4] = {bfv.x, bfv.y, bfv.z, bfv.w};
    #pragma unroll
    for (int i = 0; i < 4; ++i) {
        float4 o = { acc[i][0] + ar[0], acc[i][1] + ar[1],
                     acc[i][2] + ar[2], acc[i][3] + ar[3] };
        *(float4*)(feats + (size_t)(row0 + ty * 4 + i) * PP + tx * 4) = o;
    }

    const int cr = tid >> 2, cc = tid & 3;
    float ca = bs[cc];
    #pragma unroll 16
    for (int k = 0; k < 64; ++k) ca += Xs[k][cr] * Wss[k][cc];
    coords[(size_t)(row0 + cr) * DD + cc] = ca;
}

// ---------------------------------------------------------------------------
// select_collect: given packed 8-bit bins (4/u32), nearmask (bit j: candidate
// was histogrammed), and the filled per-wave histogram, find the rank-40
// boundary and scatter the selected indices to cp[0..KNB).
// EXACTLY equivalent to the float-compare select of R4-R6 (passing):
//   bin < g1         <=>  d2 < g1/scale  (exact pow2 scale)
//   bin == g1 & near <=>  d2 in boundary bin (far/self have near=0).
// Returns false (before collecting) if total < KNB and allow_fail.
// ---------------------------------------------------------------------------
static __device__ __forceinline__ bool select_collect(
    const unsigned int (&bp)[8], const unsigned int nearmask,
    int* __restrict__ hw, int* __restrict__ cp, const int lane,
    const bool allow_fail)
{
    int4 hv = ((const int4*)hw)[lane];
    const int local = hv.x + hv.y + hv.z + hv.w;
    const int incl  = wave_incl_scan(local);
    if (allow_fail) {
        const int total = __builtin_amdgcn_readlane(incl, 63);
        if (total < KNB) return false;
    }
    const int excl = incl - local;
    const bool pred = (excl < KNB) && (incl >= KNB);
    const unsigned long long m = __ballot(pred);
    const int src = (m == 0ull) ? 0 : ((int)__ffsll(m) - 1);  // uniform
    int gg = 0, nnb = 0;
    if (pred) {
        const int hh[4] = {hv.x, hv.y, hv.z, hv.w};
        int cacc = excl, found = -1;
        #pragma unroll
        for (int q = 0; q < 4; ++q) {
            if (found < 0 && cacc + hh[q] >= KNB) { found = q; nnb = cacc; }
            cacc += hh[q];
        }
        gg = (lane << 2) + found;
    }
    const int g1  = __builtin_amdgcn_readlane(gg,  src);
    const int nb1 = __builtin_amdgcn_readlane(nnb, src);

    // ---- masks from bin bytes (bfe + cmp; no floats) ----
    unsigned int maskA = 0u, maskB = 0u;
    #pragma unroll
    for (int j = 0; j < 32; ++j) {
        const int bb = (int)((bp[j >> 2] >> ((j & 3) * 8)) & 255u);
        if (bb < g1) maskA |= (1u << j);
        else if (bb == g1) maskB |= (1u << j);
    }
    maskB &= nearmask;                     // drop far/self sentinels (bin 255)

    const int packed = __popc(maskA) | (__popc(maskB) << 16);
    const int incl2  = wave_incl_scan(packed);
    const int excl2  = incl2 - packed;
    int baseA = excl2 & 0xFFFF;            // region A: [0, nb1)
    int baseB = nb1 + (excl2 >> 16);       // region B: [nb1, 40), capped
    #pragma unroll
    for (int j = 0; j < 32; ++j) {
        const bool a = (maskA >> j) & 1u;
        const bool b = (maskB >> j) & 1u;
        const int  dst = a ? baseA : baseB;
        if ((a | b) && (a || baseB < KNB))
            cp[dst] = lane + (j << 6);
        baseA += (int)a;
        baseB += (int)b;
    }
    return true;
}

// rebuild_fb: rare fallback — re-derive d2, bins at [0,1024) width 4, re-hist.
// Chunked (8 iters + sched_barrier) like the main loop to cap reg pressure.
static __device__ __forceinline__ void rebuild_fb(
    const float4* __restrict__ cb4, const float cvx, const float cvy,
    const float cvz, const float cvw, const int jself,
    const int lself, int* __restrict__ hw, unsigned int (&bp)[8],
    unsigned int& nearm, const int lane)
{
    const int4 izero = {0, 0, 0, 0};
    ((int4*)hw)[lane] = izero;
    nearm = 0u;
    #pragma unroll
    for (int q = 0; q < 8; ++q) bp[q] = 0u;
    #pragma unroll
    for (int c = 0; c < 4; ++c) {
        #pragma unroll
        for (int u = 0; u < 8; ++u) {
            const int j = c * 8 + u;       // compile-time constant
            const float4 cw = cb4[lane + (j << 6)];
            const float dx = cvx - cw.x, dy = cvy - cw.y;
            const float dz = cvz - cw.z, dw = cvw - cw.w;
            float d2 = dx*dx + dy*dy + dz*dz + dw*dw;
            if (j == jself && lane == lself) d2 = FLT_MAX;
            const bool nr = (d2 < 1024.f);
            const int  bb = nr ? (int)(d2 * 0.25f) : 255;
            bp[j >> 2] |= (unsigned int)bb << ((j & 3) * 8);
            nearm      |= (nr ? 1u : 0u) << j;
            if (nr) atomicAdd(&hw[bb], 1);
        }
        __builtin_amdgcn_sched_barrier(0); // cap in-flight loads per chunk
    }
}

// ---------------------------------------------------------------------------
// Kernel 2a: k_select — top-40 KNN selection, ONE row per wave, bin-packed.
// R10: hard launch bounds are pathological on this allocator (R8/R9: forced
// (256,8) -> VGPR=32 + 640MB spill). Target stays "<=64 VGPR, zero spill",
// reached NATURALLY: 1-row bin-packed state (~55 live regs incl. transients)
// + sched_barrier(0) every 8 distance iters to cap load pipelining (16
// in-flight float4 = 64 regs was the pressure peak). No launch bound.
// Signature to verify: VGPR<=64, WRITE_SIZE ~10.2MB, occupancy >=60%.
// Select semantics identical to passing R4-R9. Output: 40 u32 idx per row.
// ---------------------------------------------------------------------------
__global__ __launch_bounds__(256) void k_select(
    const float* __restrict__ coords, float* __restrict__ collected)
{
    __shared__ int hist[4][256];       // 4 KB (per-wave)
    __shared__ int candP[4][KNB];      // 640 B: neighbor idx

    const int tid   = threadIdx.x;
    const int lane  = tid & 63;
    const int w     = tid >> 6;
    // XCD swizzle: 16384 blocks, 8 XCDs -> 2048 contiguous blocks per XCD.
    const int bid   = (int)blockIdx.x;
    const int swz   = ((bid & 7) << 11) + (bid >> 3);
    // one row per wave (wave-uniform)
    const int vu    = __builtin_amdgcn_readfirstlane((swz << 2) + w);
    const int batch = vu >> 11;
    const int vloc  = vu & (VV - 1);
    const float4* cb4 = (const float4*)(coords + (size_t)batch * VV * DD);

    const int4 izero = {0, 0, 0, 0};

    // query coords -> SGPRs (uniform)
    const float4 cvv = cb4[vloc];
    const float cvx = rfl_f(cvv.x), cvy = rfl_f(cvv.y);
    const float cvz = rfl_f(cvv.z), cvw = rfl_f(cvv.w);
    const int jself = vloc >> 6;
    const int lself = vloc & 63;

    ((int4*)hist[w])[lane] = izero;

    // ---- fused distance + bin-pack + histogram, 4 chunks of 8 ----
    unsigned int bp[8] = {0,0,0,0,0,0,0,0};
    unsigned int nearm = 0u;
    #pragma unroll
    for (int c = 0; c < 4; ++c) {
        #pragma unroll
        for (int u = 0; u < 8; ++u) {
            const int j = c * 8 + u;       // compile-time constant
            const float4 cw = cb4[lane + (j << 6)];
            const float dx = cvx - cw.x, dy = cvy - cw.y;
            const float dz = cvz - cw.z, dw = cvw - cw.w;
            float d2 = dx*dx + dy*dy + dz*dz + dw*dw;
            if (j == jself && lane == lself) d2 = FLT_MAX;  // self -> sentinel
            const bool nr = (d2 < 4.f);
            const int  bb = nr ? (int)(d2 * 64.f) : 255;
            bp[j >> 2] |= (unsigned int)bb << ((j & 3) * 8);
            nearm      |= (nr ? 1u : 0u) << j;
            if (nr) atomicAdd(&hist[w][bb], 1);
        }
        __builtin_amdgcn_sched_barrier(0); // cap in-flight loads per chunk
    }

    // ---- select + collect (fallback rare, wave-uniform) ----
    if (!select_collect(bp, nearm, hist[w], candP[w], lane, true)) {
        rebuild_fb(cb4, cvx, cvy, cvz, cvw, jself, lself,
                   hist[w], bp, nearm, lane);
        select_collect(bp, nearm, hist[w], candP[w], lane, false);
    }

    // ---- lanes 0..39: coalesced idx write to the row slot ----
    if (lane < KNB) {
        const unsigned int u0 = (unsigned int)candP[w][lane];
        ((unsigned int*)(collected + ((size_t)vu << 7)))[lane] = u0;
    }
}

// ---------------------------------------------------------------------------
// Kernel 2b: k_pool — gather 40 neighbor feature rows, weighted max/mean.
// (unchanged from R7-R9, passing): weight exp(-10*d2) recomputed here from
// coords (full fp32), readlane -> SGPR idx/weight, saddr gathers, row slot
// overwritten with pooled output.
// ---------------------------------------------------------------------------
__global__ __launch_bounds__(256) void k_pool(
    const float* __restrict__ coords, const float* __restrict__ feats,
    float* __restrict__ collected)
{
    const int tid  = threadIdx.x;
    const int lane = tid & 63;
    const int w4   = tid >> 6;             // wave in block: 0..3
    // XCD swizzle: 16384 blocks, 8 XCDs -> 2048 contiguous blocks per XCD.
    const int bid  = (int)blockIdx.x;
    const int swz  = ((bid & 7) << 11) + (bid >> 3);
    const int v    = (swz << 2) + w4;      // global row
    const int batch = v >> 11;
    const float*  fb  = feats + (size_t)batch * VV * PP;
    const float4* cb4 = (const float4*)(coords + (size_t)batch * VV * DD);
    float* rowp = collected + ((size_t)v << 7);

    // packed candidates + per-lane weight (lanes 0..39), before overwrite
    unsigned int u = 0u; float wgt = 0.f;
    if (lane < KNB) {
        u = ((const unsigned int*)rowp)[lane];
        const float4 cv = cb4[v & (VV - 1)];
        const float4 cw = cb4[u];
        const float dx = cv.x - cw.x, dy = cv.y - cw.y;
        const float dz = cv.z - cw.z, dw = cv.w - cw.w;
        wgt = __expf(-10.f * (dx*dx + dy*dy + dz*dz + dw*dw));
    }

    float mx = -FLT_MAX, sm = 0.f;
    #pragma unroll
    for (int j0 = 0; j0 < KNB; j0 += 20) {
        float fv[20]; float wv[20];
        #pragma unroll
        for (int t = 0; t < 20; ++t) {
            const int si = __builtin_amdgcn_readlane((int)u, j0 + t);   // SGPR
            wv[t] = __uint_as_float(
                (unsigned int)__builtin_amdgcn_readlane(__float_as_int(wgt), j0 + t));
            fv[t] = fb[(size_t)(si * PP) + lane];                       // saddr
        }
        #pragma unroll
        for (int t = 0; t < 20; ++t) {
            const float nv = fv[t] * wv[t];
            mx = fmaxf(mx, nv);
            sm += nv;
        }
    }
    rowp[lane]      = mx;
    rowp[PP + lane] = sm * (1.f / KNB);
}

// ---------------------------------------------------------------------------
// Kernel 3: out = tanh(concat(x, collected) @ W_out + b_out), (N x 192)@(192 x 128)
// (unchanged, passing)
// ---------------------------------------------------------------------------
__global__ __launch_bounds__(256) void k_out(
    const float* __restrict__ x, const float* __restrict__ collected,
    const float* __restrict__ Wout, const float* __restrict__ bout,
    float* __restrict__ out)
{
    __shared__ float As[16][68];   // [kk][r], +4 pad
    __shared__ float Bs[16][128];
    const int tid = threadIdx.x;
    const int tx  = tid & 15;
    const int ty  = tid >> 4;
    const int row0 = blockIdx.x * 64;

    float acc[4][8];
    #pragma unroll
    for (int i = 0; i < 4; ++i)
        #pragma unroll
        for (int j = 0; j < 8; ++j) acc[i][j] = 0.f;

    for (int k0 = 0; k0 < 192; k0 += 16) {
        {   // stage A tile transposed: thread loads (r, kk4..kk4+3), scatters
            const int r   = tid >> 2;
            const int kk4 = (tid & 3) << 2;
            const float* src = (k0 < 64)
                ? (x + (size_t)(row0 + r) * FIN + (k0 + kk4))
                : (collected + (size_t)(row0 + r) * 128 + (k0 - 64 + kk4));
            float4 v = *(const float4*)src;
            As[kk4+0][r] = v.x; As[kk4+1][r] = v.y;
            As[kk4+2][r] = v.z; As[kk4+3][r] = v.w;
        }
        #pragma unroll
        for (int rep = 0; rep < 2; ++rep) {
            const int e = (tid + rep * 256) * 4;
            const int kk = e >> 7, c = e & 127;
            *(float4*)&Bs[kk][c] = *(const float4*)(Wout + (size_t)(k0 + kk) * 128 + c);
        }
        __syncthreads();
        #pragma unroll
        for (int kk = 0; kk < 16; ++kk) {
            float4 a  = *(const float4*)&As[kk][ty * 4];
            float4 b0 = *(const float4*)&Bs[kk][tx * 4];
            float4 b1 = *(const float4*)&Bs[kk][64 + tx * 4];
            const float av[4] = {a.x, a.y, a.z, a.w};
            #pragma unroll
            for (int i = 0; i < 4; ++i) {
                acc[i][0] += av[i] * b0.x; acc[i][1] += av[i] * b0.y;
                acc[i][2] += av[i] * b0.z; acc[i][3] += av[i] * b0.w;
                acc[i][4] += av[i] * b1.x; acc[i][5] += av[i] * b1.y;
                acc[i][6] += av[i] * b1.z; acc[i][7] += av[i] * b1.w;
            }
        }
        __syncthreads();
    }

    #pragma unroll
    for (int i = 0; i < 4; ++i) {
        const int row = row0 + ty * 4 + i;
        float4 o0, o1;
        o0.x = fast_tanh(acc[i][0] + bout[tx*4+0]);
        o0.y = fast_tanh(acc[i][1] + bout[tx*4+1]);
        o0.z = fast_tanh(acc[i][2] + bout[tx*4+2]);
        o0.w = fast_tanh(acc[i][3] + bout[tx*4+3]);
        o1.x = fast_tanh(acc[i][4] + bout[64+tx*4+0]);
        o1.y = fast_tanh(acc[i][5] + bout[64+tx*4+1]);
        o1.z = fast_tanh(acc[i][6] + bout[64+tx*4+2]);
        o1.w = fast_tanh(acc[i][7] + bout[64+tx*4+3]);
        *(float4*)(out + (size_t)row * 128 + tx * 4)      = o0;
        *(float4*)(out + (size_t)row * 128 + 64 + tx * 4) = o1;
    }
}

// ---------------------------------------------------------------------------
extern "C" void kernel_launch(void* const* d_in, const int* in_sizes, int n_in,
                              void* d_out, int out_size, void* d_ws, size_t ws_size,
                              hipStream_t stream)
{
    const float* x    = (const float*)d_in[0];
    // d_in[1] = row_splits: uniform arange(B+1)*V — fixed structure, unused.
    const float* Ws   = (const float*)d_in[2];
    const float* bs   = (const float*)d_in[3];
    const float* Wf   = (const float*)d_in[4];
    const float* bf   = (const float*)d_in[5];
    const float* Wout = (const float*)d_in[6];
    const float* bout = (const float*)d_in[7];
    float* out = (float*)d_out;

    float* coords = (float*)d_ws;                                            // 1 MB
    float* feats  = (float*)((char*)d_ws + (size_t)NN * DD * sizeof(float)); // 16 MB
    float* collected = out;   // reuse d_out as scratch for pooled features

    hipLaunchKernelGGL(k_embed, dim3(NN / 64), dim3(256), 0, stream,
                       x, Ws, bs, Wf, bf, coords, feats);
    // selection: 1 row per wave, 4 waves/block -> 16384 blocks
    hipLaunchKernelGGL(k_select, dim3(NN / 4), dim3(256), 0, stream,
                       coords, collected);
    // pooling: 1 row per wave, 4 waves/block -> 16384 blocks
    hipLaunchKernelGGL(k_pool, dim3(NN / 4), dim3(256), 0, stream,
                       coords, feats, collected);
    hipLaunchKernelGGL(k_out, dim3(NN / 64), dim3(256), 0, stream,
                       x, collected, Wout, bout, out);
}

// Round 11
// 344.594 us; speedup vs baseline: 1.3577x; 1.0785x over previous
//
#include <hip/hip_runtime.h>
#include <cfloat>

#define BB   32
#define VV   2048
#define KNB  40
#define FIN  64
#define DD   4
#define PP   64
#define NN   (BB*VV)           // 65536

static __device__ __forceinline__ float fast_tanh(float z) {
    z = fminf(fmaxf(z, -15.f), 15.f);
    float e = __expf(2.f * z);
    return (e - 1.f) / (e + 1.f);
}

static __device__ __forceinline__ float rfl_f(float x) {
    return __uint_as_float(
        (unsigned)__builtin_amdgcn_readfirstlane(__float_as_int(x)));
}

// Wave64 inclusive add-scan via DPP (rocPRIM pattern): 6 VALU ops, no DS pipe.
static __device__ __forceinline__ int wave_incl_scan(int x) {
    x += __builtin_amdgcn_update_dpp(0, x, 0x111, 0xf, 0xf, true); // row_shr:1
    x += __builtin_amdgcn_update_dpp(0, x, 0x112, 0xf, 0xf, true); // row_shr:2
    x += __builtin_amdgcn_update_dpp(0, x, 0x114, 0xf, 0xf, true); // row_shr:4
    x += __builtin_amdgcn_update_dpp(0, x, 0x118, 0xf, 0xf, true); // row_shr:8
    x += __builtin_amdgcn_update_dpp(0, x, 0x142, 0xa, 0xf, true); // row_bcast:15 -> rows 1,3
    x += __builtin_amdgcn_update_dpp(0, x, 0x143, 0xc, 0xf, true); // row_bcast:31 -> rows 2,3
    return x;
}

// ---------------------------------------------------------------------------
// Kernel 1: coords = x@W_s + b_s (N x 4), feats = x@W_f + b_f (N x 64)
// (unchanged, passing)
// ---------------------------------------------------------------------------
__global__ __launch_bounds__(256) void k_embed(
    const float* __restrict__ x, const float* __restrict__ Ws,
    const float* __restrict__ bs, const float* __restrict__ Wf,
    const float* __restrict__ bf, float* __restrict__ coords,
    float* __restrict__ feats)
{
    __shared__ float Xs[64][68];
    __shared__ float Wfs[64][64];
    __shared__ float Wss[64][4];
    const int tid  = threadIdx.x;
    const int row0 = blockIdx.x * 64;

    #pragma unroll
    for (int i = 0; i < 4; ++i) {
        const int idx = tid + i * 256;
        const int r   = idx >> 4;
        const int k4  = (idx & 15) << 2;
        float4 v = *(const float4*)(x + (size_t)(row0 + r) * FIN + k4);
        Xs[k4+0][r] = v.x; Xs[k4+1][r] = v.y; Xs[k4+2][r] = v.z; Xs[k4+3][r] = v.w;
        ((float4*)Wfs)[idx] = ((const float4*)Wf)[idx];
    }
    if (tid < 64) *(float4*)Wss[tid] = ((const float4*)Ws)[tid];
    __syncthreads();

    const int tx = tid & 15;
    const int ty = tid >> 4;
    float acc[4][4] = {};
    #pragma unroll 16
    for (int k = 0; k < 64; ++k) {
        float4 a = *(const float4*)&Xs[k][ty * 4];
        float4 b = *(const float4*)&Wfs[k][tx * 4];
        acc[0][0] += a.x*b.x; acc[0][1] += a.x*b.y; acc[0][2] += a.x*b.z; acc[0][3] += a.x*b.w;
        acc[1][0] += a.y*b.x; acc[1][1] += a.y*b.y; acc[1][2] += a.y*b.z; acc[1][3] += a.y*b.w;
        acc[2][0] += a.z*b.x; acc[2][1] += a.z*b.y; acc[2][2] += a.z*b.z; acc[2][3] += a.z*b.w;
        acc[3][0] += a.w*b.x; acc[3][1] += a.w*b.y; acc[3][2] += a.w*b.z; acc[3][3] += a.w*b.w;
    }
    const float4 bfv = *(const float4*)(bf + tx * 4);
    const float ar[4] = {bfv.x, bfv.y, bfv.z, bfv.w};
    #pragma unroll
    for (int i = 0; i < 4; ++i) {
        float4 o = { acc[i][0] + ar[0], acc[i][1] + ar[1],
                     acc[i][2] + ar[2], acc[i][3] + ar[3] };
        *(float4*)(feats + (size_t)(row0 + ty * 4 + i) * PP + tx * 4) = o;
    }

    const int cr = tid >> 2, cc = tid & 3;
    float ca = bs[cc];
    #pragma unroll 16
    for (int k = 0; k < 64; ++k) ca += Xs[k][cr] * Wss[k][cc];
    coords[(size_t)(row0 + cr) * DD + cc] = ca;
}

// ---------------------------------------------------------------------------
// select_collect: bins now live in per-lane LDS (binsL: 8 u32 = 32 bytes).
// Read back via two ds_read_b128 into transient regs; masks built from byte
// extracts. Selection semantics EXACTLY the float-compare select of R4-R10:
//   bin < g1         <=>  d2 < g1/scale  (exact pow2 scale)
//   bin == g1 & near <=>  d2 in boundary bin (far/self have near=0).
// Returns false (before collecting) if total < KNB and allow_fail.
// ---------------------------------------------------------------------------
static __device__ __forceinline__ bool select_collect(
    const unsigned int* __restrict__ binsL, const unsigned int nearmask,
    int* __restrict__ hw, int* __restrict__ cp, const int lane,
    const bool allow_fail)
{
    int4 hv = ((const int4*)hw)[lane];
    const int local = hv.x + hv.y + hv.z + hv.w;
    const int incl  = wave_incl_scan(local);
    if (allow_fail) {
        const int total = __builtin_amdgcn_readlane(incl, 63);
        if (total < KNB) return false;
    }
    const int excl = incl - local;
    const bool pred = (excl < KNB) && (incl >= KNB);
    const unsigned long long m = __ballot(pred);
    const int src = (m == 0ull) ? 0 : ((int)__ffsll(m) - 1);  // uniform
    int gg = 0, nnb = 0;
    if (pred) {
        const int hh[4] = {hv.x, hv.y, hv.z, hv.w};
        int cacc = excl, found = -1;
        #pragma unroll
        for (int q = 0; q < 4; ++q) {
            if (found < 0 && cacc + hh[q] >= KNB) { found = q; nnb = cacc; }
            cacc += hh[q];
        }
        gg = (lane << 2) + found;
    }
    const int g1  = __builtin_amdgcn_readlane(gg,  src);
    const int nb1 = __builtin_amdgcn_readlane(nnb, src);

    // ---- bins back from LDS (2x ds_read_b128, transient) ----
    const uint4 w0 = ((const uint4*)binsL)[0];
    const uint4 w1 = ((const uint4*)binsL)[1];
    const unsigned int bw[8] = {w0.x, w0.y, w0.z, w0.w,
                                w1.x, w1.y, w1.z, w1.w};

    // ---- masks from bin bytes (bfe + cmp; no floats) ----
    unsigned int maskA = 0u, maskB = 0u;
    #pragma unroll
    for (int j = 0; j < 32; ++j) {
        const int bb = (int)((bw[j >> 2] >> ((j & 3) * 8)) & 255u);
        if (bb < g1) maskA |= (1u << j);
        else if (bb == g1) maskB |= (1u << j);
    }
    maskB &= nearmask;                     // drop far/self sentinels (bin 255)

    const int packed = __popc(maskA) | (__popc(maskB) << 16);
    const int incl2  = wave_incl_scan(packed);
    const int excl2  = incl2 - packed;
    int baseA = excl2 & 0xFFFF;            // region A: [0, nb1)
    int baseB = nb1 + (excl2 >> 16);       // region B: [nb1, 40), capped
    #pragma unroll
    for (int j = 0; j < 32; ++j) {
        const bool a = (maskA >> j) & 1u;
        const bool b = (maskB >> j) & 1u;
        const int  dst = a ? baseA : baseB;
        if ((a | b) && (a || baseB < KNB))
            cp[dst] = lane + (j << 6);
        baseA += (int)a;
        baseB += (int)b;
    }
    return true;
}

// rebuild_fb: rare fallback — re-derive d2, bins at [0,1024) width 4, re-hist.
// Same LDS-bin staging + chunked scheduling as the main loop.
static __device__ __forceinline__ void rebuild_fb(
    const float4* __restrict__ cb4, const float cvx, const float cvy,
    const float cvz, const float cvw, const int jself,
    const int lself, int* __restrict__ hw, unsigned int* __restrict__ binsL,
    unsigned int& nearm, const int lane)
{
    const int4 izero = {0, 0, 0, 0};
    ((int4*)hw)[lane] = izero;
    nearm = 0u;
    #pragma unroll
    for (int q = 0; q < 8; ++q) {
        unsigned int wq = 0u;
        #pragma unroll
        for (int t = 0; t < 4; ++t) {
            const int j = q * 4 + t;       // compile-time constant
            const float4 cw = cb4[lane + (j << 6)];
            const float dx = cvx - cw.x, dy = cvy - cw.y;
            const float dz = cvz - cw.z, dw = cvw - cw.w;
            float d2 = dx*dx + dy*dy + dz*dz + dw*dw;
            if (j == jself && lane == lself) d2 = FLT_MAX;
            const bool nr = (d2 < 1024.f);
            const int  bb = nr ? (int)(d2 * 0.25f) : 255;
            wq    |= (unsigned int)bb << (t * 8);
            nearm |= (nr ? 1u : 0u) << j;
            if (nr) atomicAdd(&hw[bb], 1);
        }
        binsL[q] = wq;                     // ds_write_b32
        if (q & 1) __builtin_amdgcn_sched_barrier(0); // cap in-flight loads
    }
}

// ---------------------------------------------------------------------------
// Kernel 2a: k_select — top-40 KNN, ONE row per wave, bins in per-lane LDS.
// R11: R10 landed VGPR=68 (4 over the 8-waves/SIMD boundary), occ 33%,
// 229us, zero spill. The persistent bp[8] is 8 of those 68. Fix: stage bins
// in LDS (bins[4][64][8] u32 = 8KB/block) — write-once in the distance loop
// (8x ds_write_b32), read-once in collect (2x ds_read_b128, transient).
// Expected VGPR ~60 -> natural 8-waves/SIMD tier, NO launch bound (R8/R9:
// forcing is pathological). Select semantics identical to passing R4-R10.
// Signature to verify: VGPR<=64, WRITE ~10.2MB, occ>=50%.
// ---------------------------------------------------------------------------
__global__ __launch_bounds__(256) void k_select(
    const float* __restrict__ coords, float* __restrict__ collected)
{
    __shared__ int hist[4][256];             // 4 KB (per-wave)
    __shared__ int candP[4][KNB];            // 640 B: neighbor idx
    __shared__ unsigned int binsLDS[4][64][8]; // 8 KB: per-lane bins

    const int tid   = threadIdx.x;
    const int lane  = tid & 63;
    const int w     = tid >> 6;
    // XCD swizzle: 16384 blocks, 8 XCDs -> 2048 contiguous blocks per XCD.
    const int bid   = (int)blockIdx.x;
    const int swz   = ((bid & 7) << 11) + (bid >> 3);
    // one row per wave (wave-uniform)
    const int vu    = __builtin_amdgcn_readfirstlane((swz << 2) + w);
    const int batch = vu >> 11;
    const int vloc  = vu & (VV - 1);
    const float4* cb4 = (const float4*)(coords + (size_t)batch * VV * DD);
    unsigned int* binsL = binsLDS[w][lane];

    const int4 izero = {0, 0, 0, 0};

    // query coords -> SGPRs (uniform)
    const float4 cvv = cb4[vloc];
    const float cvx = rfl_f(cvv.x), cvy = rfl_f(cvv.y);
    const float cvz = rfl_f(cvv.z), cvw = rfl_f(cvv.w);
    const int jself = vloc >> 6;
    const int lself = vloc & 63;

    ((int4*)hist[w])[lane] = izero;

    // ---- fused distance + bin-pack(->LDS) + histogram ----
    unsigned int nearm = 0u;
    #pragma unroll
    for (int q = 0; q < 8; ++q) {
        unsigned int wq = 0u;
        #pragma unroll
        for (int t = 0; t < 4; ++t) {
            const int j = q * 4 + t;       // compile-time constant
            const float4 cw = cb4[lane + (j << 6)];
            const float dx = cvx - cw.x, dy = cvy - cw.y;
            const float dz = cvz - cw.z, dw = cvw - cw.w;
            float d2 = dx*dx + dy*dy + dz*dz + dw*dw;
            if (j == jself && lane == lself) d2 = FLT_MAX;  // self -> sentinel
            const bool nr = (d2 < 4.f);
            const int  bb = nr ? (int)(d2 * 64.f) : 255;
            wq    |= (unsigned int)bb << (t * 8);
            nearm |= (nr ? 1u : 0u) << j;
            if (nr) atomicAdd(&hist[w][bb], 1);
        }
        binsL[q] = wq;                     // ds_write_b32
        if (q & 1) __builtin_amdgcn_sched_barrier(0); // cap in-flight loads
    }

    // ---- select + collect (fallback rare, wave-uniform) ----
    if (!select_collect(binsL, nearm, hist[w], candP[w], lane, true)) {
        rebuild_fb(cb4, cvx, cvy, cvz, cvw, jself, lself,
                   hist[w], binsL, nearm, lane);
        select_collect(binsL, nearm, hist[w], candP[w], lane, false);
    }

    // ---- lanes 0..39: coalesced idx write to the row slot ----
    if (lane < KNB) {
        const unsigned int u0 = (unsigned int)candP[w][lane];
        ((unsigned int*)(collected + ((size_t)vu << 7)))[lane] = u0;
    }
}

// ---------------------------------------------------------------------------
// Kernel 2b: k_pool — gather 40 neighbor feature rows, weighted max/mean.
// (unchanged from R7-R10, passing): weight exp(-10*d2) recomputed here from
// coords (full fp32), readlane -> SGPR idx/weight, saddr gathers, row slot
// overwritten with pooled output.
// ---------------------------------------------------------------------------
__global__ __launch_bounds__(256) void k_pool(
    const float* __restrict__ coords, const float* __restrict__ feats,
    float* __restrict__ collected)
{
    const int tid  = threadIdx.x;
    const int lane = tid & 63;
    const int w4   = tid >> 6;             // wave in block: 0..3
    // XCD swizzle: 16384 blocks, 8 XCDs -> 2048 contiguous blocks per XCD.
    const int bid  = (int)blockIdx.x;
    const int swz  = ((bid & 7) << 11) + (bid >> 3);
    const int v    = (swz << 2) + w4;      // global row
    const int batch = v >> 11;
    const float*  fb  = feats + (size_t)batch * VV * PP;
    const float4* cb4 = (const float4*)(coords + (size_t)batch * VV * DD);
    float* rowp = collected + ((size_t)v << 7);

    // packed candidates + per-lane weight (lanes 0..39), before overwrite
    unsigned int u = 0u; float wgt = 0.f;
    if (lane < KNB) {
        u = ((const unsigned int*)rowp)[lane];
        const float4 cv = cb4[v & (VV - 1)];
        const float4 cw = cb4[u];
        const float dx = cv.x - cw.x, dy = cv.y - cw.y;
        const float dz = cv.z - cw.z, dw = cv.w - cw.w;
        wgt = __expf(-10.f * (dx*dx + dy*dy + dz*dz + dw*dw));
    }

    float mx = -FLT_MAX, sm = 0.f;
    #pragma unroll
    for (int j0 = 0; j0 < KNB; j0 += 20) {
        float fv[20]; float wv[20];
        #pragma unroll
        for (int t = 0; t < 20; ++t) {
            const int si = __builtin_amdgcn_readlane((int)u, j0 + t);   // SGPR
            wv[t] = __uint_as_float(
                (unsigned int)__builtin_amdgcn_readlane(__float_as_int(wgt), j0 + t));
            fv[t] = fb[(size_t)(si * PP) + lane];                       // saddr
        }
        #pragma unroll
        for (int t = 0; t < 20; ++t) {
            const float nv = fv[t] * wv[t];
            mx = fmaxf(mx, nv);
            sm += nv;
        }
    }
    rowp[lane]      = mx;
    rowp[PP + lane] = sm * (1.f / KNB);
}

// ---------------------------------------------------------------------------
// Kernel 3: out = tanh(concat(x, collected) @ W_out + b_out), (N x 192)@(192 x 128)
// (unchanged, passing)
// ---------------------------------------------------------------------------
__global__ __launch_bounds__(256) void k_out(
    const float* __restrict__ x, const float* __restrict__ collected,
    const float* __restrict__ Wout, const float* __restrict__ bout,
    float* __restrict__ out)
{
    __shared__ float As[16][68];   // [kk][r], +4 pad
    __shared__ float Bs[16][128];
    const int tid = threadIdx.x;
    const int tx  = tid & 15;
    const int ty  = tid >> 4;
    const int row0 = blockIdx.x * 64;

    float acc[4][8];
    #pragma unroll
    for (int i = 0; i < 4; ++i)
        #pragma unroll
        for (int j = 0; j < 8; ++j) acc[i][j] = 0.f;

    for (int k0 = 0; k0 < 192; k0 += 16) {
        {   // stage A tile transposed: thread loads (r, kk4..kk4+3), scatters
            const int r   = tid >> 2;
            const int kk4 = (tid & 3) << 2;
            const float* src = (k0 < 64)
                ? (x + (size_t)(row0 + r) * FIN + (k0 + kk4))
                : (collected + (size_t)(row0 + r) * 128 + (k0 - 64 + kk4));
            float4 v = *(const float4*)src;
            As[kk4+0][r] = v.x; As[kk4+1][r] = v.y;
            As[kk4+2][r] = v.z; As[kk4+3][r] = v.w;
        }
        #pragma unroll
        for (int rep = 0; rep < 2; ++rep) {
            const int e = (tid + rep * 256) * 4;
            const int kk = e >> 7, c = e & 127;
            *(float4*)&Bs[kk][c] = *(const float4*)(Wout + (size_t)(k0 + kk) * 128 + c);
        }
        __syncthreads();
        #pragma unroll
        for (int kk = 0; kk < 16; ++kk) {
            float4 a  = *(const float4*)&As[kk][ty * 4];
            float4 b0 = *(const float4*)&Bs[kk][tx * 4];
            float4 b1 = *(const float4*)&Bs[kk][64 + tx * 4];
            const float av[4] = {a.x, a.y, a.z, a.w};
            #pragma unroll
            for (int i = 0; i < 4; ++i) {
                acc[i][0] += av[i] * b0.x; acc[i][1] += av[i] * b0.y;
                acc[i][2] += av[i] * b0.z; acc[i][3] += av[i] * b0.w;
                acc[i][4] += av[i] * b1.x; acc[i][5] += av[i] * b1.y;
                acc[i][6] += av[i] * b1.z; acc[i][7] += av[i] * b1.w;
            }
        }
        __syncthreads();
    }

    #pragma unroll
    for (int i = 0; i < 4; ++i) {
        const int row = row0 + ty * 4 + i;
        float4 o0, o1;
        o0.x = fast_tanh(acc[i][0] + bout[tx*4+0]);
        o0.y = fast_tanh(acc[i][1] + bout[tx*4+1]);
        o0.z = fast_tanh(acc[i][2] + bout[tx*4+2]);
        o0.w = fast_tanh(acc[i][3] + bout[tx*4+3]);
        o1.x = fast_tanh(acc[i][4] + bout[64+tx*4+0]);
        o1.y = fast_tanh(acc[i][5] + bout[64+tx*4+1]);
        o1.z = fast_tanh(acc[i][6] + bout[64+tx*4+2]);
        o1.w = fast_tanh(acc[i][7] + bout[64+tx*4+3]);
        *(float4*)(out + (size_t)row * 128 + tx * 4)      = o0;
        *(float4*)(out + (size_t)row * 128 + 64 + tx * 4) = o1;
    }
}

// ---------------------------------------------------------------------------
extern "C" void kernel_launch(void* const* d_in, const int* in_sizes, int n_in,
                              void* d_out, int out_size, void* d_ws, size_t ws_size,
                              hipStream_t stream)
{
    const float* x    = (const float*)d_in[0];
    // d_in[1] = row_splits: uniform arange(B+1)*V — fixed structure, unused.
    const float* Ws   = (const float*)d_in[2];
    const float* bs   = (const float*)d_in[3];
    const float* Wf   = (const float*)d_in[4];
    const float* bf   = (const float*)d_in[5];
    const float* Wout = (const float*)d_in[6];
    const float* bout = (const float*)d_in[7];
    float* out = (float*)d_out;

    float* coords = (float*)d_ws;                                            // 1 MB
    float* feats  = (float*)((char*)d_ws + (size_t)NN * DD * sizeof(float)); // 16 MB
    float* collected = out;   // reuse d_out as scratch for pooled features

    hipLaunchKernelGGL(k_embed, dim3(NN / 64), dim3(256), 0, stream,
                       x, Ws, bs, Wf, bf, coords, feats);
    // selection: 1 row per wave, 4 waves/block -> 16384 blocks
    hipLaunchKernelGGL(k_select, dim3(NN / 4), dim3(256), 0, stream,
                       coords, collected);
    // pooling: 1 row per wave, 4 waves/block -> 16384 blocks
    hipLaunchKernelGGL(k_pool, dim3(NN / 4), dim3(256), 0, stream,
                       coords, feats, collected);
    hipLaunchKernelGGL(k_out, dim3(NN / 64), dim3(256), 0, stream,
                       x, collected, Wout, bout, out);
}

// Round 12
// 324.370 us; speedup vs baseline: 1.4424x; 1.0624x over previous
//
#include <hip/hip_runtime.h>
#include <cfloat>

#define BB   32
#define VV   2048
#define KNB  40
#define FIN  64
#define DD   4
#define PP   64
#define NN   (BB*VV)           // 65536

static __device__ __forceinline__ float fast_tanh(float z) {
    z = fminf(fmaxf(z, -15.f), 15.f);
    float e = __expf(2.f * z);
    return (e - 1.f) / (e + 1.f);
}

static __device__ __forceinline__ float rfl_f(float x) {
    return __uint_as_float(
        (unsigned)__builtin_amdgcn_readfirstlane(__float_as_int(x)));
}

// Wave64 inclusive add-scan via DPP (rocPRIM pattern): 6 VALU ops, no DS pipe.
static __device__ __forceinline__ int wave_incl_scan(int x) {
    x += __builtin_amdgcn_update_dpp(0, x, 0x111, 0xf, 0xf, true); // row_shr:1
    x += __builtin_amdgcn_update_dpp(0, x, 0x112, 0xf, 0xf, true); // row_shr:2
    x += __builtin_amdgcn_update_dpp(0, x, 0x114, 0xf, 0xf, true); // row_shr:4
    x += __builtin_amdgcn_update_dpp(0, x, 0x118, 0xf, 0xf, true); // row_shr:8
    x += __builtin_amdgcn_update_dpp(0, x, 0x142, 0xa, 0xf, true); // row_bcast:15 -> rows 1,3
    x += __builtin_amdgcn_update_dpp(0, x, 0x143, 0xc, 0xf, true); // row_bcast:31 -> rows 2,3
    return x;
}

// ---------------------------------------------------------------------------
// Kernel 1: coords = x@W_s + b_s (N x 4), feats = x@W_f + b_f (N x 64)
// (unchanged, passing)
// ---------------------------------------------------------------------------
__global__ __launch_bounds__(256) void k_embed(
    const float* __restrict__ x, const float* __restrict__ Ws,
    const float* __restrict__ bs, const float* __restrict__ Wf,
    const float* __restrict__ bf, float* __restrict__ coords,
    float* __restrict__ feats)
{
    __shared__ float Xs[64][68];
    __shared__ float Wfs[64][64];
    __shared__ float Wss[64][4];
    const int tid  = threadIdx.x;
    const int row0 = blockIdx.x * 64;

    #pragma unroll
    for (int i = 0; i < 4; ++i) {
        const int idx = tid + i * 256;
        const int r   = idx >> 4;
        const int k4  = (idx & 15) << 2;
        float4 v = *(const float4*)(x + (size_t)(row0 + r) * FIN + k4);
        Xs[k4+0][r] = v.x; Xs[k4+1][r] = v.y; Xs[k4+2][r] = v.z; Xs[k4+3][r] = v.w;
        ((float4*)Wfs)[idx] = ((const float4*)Wf)[idx];
    }
    if (tid < 64) *(float4*)Wss[tid] = ((const float4*)Ws)[tid];
    __syncthreads();

    const int tx = tid & 15;
    const int ty = tid >> 4;
    float acc[4][4] = {};
    #pragma unroll 16
    for (int k = 0; k < 64; ++k) {
        float4 a = *(const float4*)&Xs[k][ty * 4];
        float4 b = *(const float4*)&Wfs[k][tx * 4];
        acc[0][0] += a.x*b.x; acc[0][1] += a.x*b.y; acc[0][2] += a.x*b.z; acc[0][3] += a.x*b.w;
        acc[1][0] += a.y*b.x; acc[1][1] += a.y*b.y; acc[1][2] += a.y*b.z; acc[1][3] += a.y*b.w;
        acc[2][0] += a.z*b.x; acc[2][1] += a.z*b.y; acc[2][2] += a.z*b.z; acc[2][3] += a.z*b.w;
        acc[3][0] += a.w*b.x; acc[3][1] += a.w*b.y; acc[3][2] += a.w*b.z; acc[3][3] += a.w*b.w;
    }
    const float4 bfv = *(const float4*)(bf + tx * 4);
    const float ar[4] = {bfv.x, bfv.y, bfv.z, bfv.w};
    #pragma unroll
    for (int i = 0; i < 4; ++i) {
        float4 o = { acc[i][0] + ar[0], acc[i][1] + ar[1],
                     acc[i][2] + ar[2], acc[i][3] + ar[3] };
        *(float4*)(feats + (size_t)(row0 + ty * 4 + i) * PP + tx * 4) = o;
    }

    const int cr = tid >> 2, cc = tid & 3;
    float ca = bs[cc];
    #pragma unroll 16
    for (int k = 0; k < 64; ++k) ca += Xs[k][cr] * Wss[k][cc];
    coords[(size_t)(row0 + cr) * DD + cc] = ca;
}

// ---------------------------------------------------------------------------
// select_collect: bins live in per-wave TRANSPOSED LDS binsW[8][64] (R12:
// lane-major => conflict-free; R11's [64][8] was a 16-way conflict, 11.3M).
// Selection semantics EXACTLY the float-compare select of R4-R11:
//   bin < g1         <=>  d2 < g1/scale  (exact pow2 scale)
//   bin == g1 & near <=>  d2 in boundary bin (far/self have near=0).
// Returns false (before collecting) if total < KNB and allow_fail.
// ---------------------------------------------------------------------------
static __device__ __forceinline__ bool select_collect(
    const unsigned int (&binsW)[8][64], const unsigned int nearmask,
    int* __restrict__ hw, int* __restrict__ cp, const int lane,
    const bool allow_fail)
{
    int4 hv = ((const int4*)hw)[lane];
    const int local = hv.x + hv.y + hv.z + hv.w;
    const int incl  = wave_incl_scan(local);
    if (allow_fail) {
        const int total = __builtin_amdgcn_readlane(incl, 63);
        if (total < KNB) return false;
    }
    const int excl = incl - local;
    const bool pred = (excl < KNB) && (incl >= KNB);
    const unsigned long long m = __ballot(pred);
    const int src = (m == 0ull) ? 0 : ((int)__ffsll(m) - 1);  // uniform
    int gg = 0, nnb = 0;
    if (pred) {
        const int hh[4] = {hv.x, hv.y, hv.z, hv.w};
        int cacc = excl, found = -1;
        #pragma unroll
        for (int q = 0; q < 4; ++q) {
            if (found < 0 && cacc + hh[q] >= KNB) { found = q; nnb = cacc; }
            cacc += hh[q];
        }
        gg = (lane << 2) + found;
    }
    const int g1  = __builtin_amdgcn_readlane(gg,  src);
    const int nb1 = __builtin_amdgcn_readlane(nnb, src);

    // ---- bins back from LDS (8x conflict-free ds_read_b32, transient) ----
    unsigned int bw[8];
    #pragma unroll
    for (int q = 0; q < 8; ++q) bw[q] = binsW[q][lane];

    // ---- masks from bin bytes (bfe + cmp; no floats) ----
    unsigned int maskA = 0u, maskB = 0u;
    #pragma unroll
    for (int j = 0; j < 32; ++j) {
        const int bb = (int)((bw[j >> 2] >> ((j & 3) * 8)) & 255u);
        if (bb < g1) maskA |= (1u << j);
        else if (bb == g1) maskB |= (1u << j);
    }
    maskB &= nearmask;                     // drop far/self sentinels (bin 255)

    const int packed = __popc(maskA) | (__popc(maskB) << 16);
    const int incl2  = wave_incl_scan(packed);
    const int excl2  = incl2 - packed;
    int baseA = excl2 & 0xFFFF;            // region A: [0, nb1)
    int baseB = nb1 + (excl2 >> 16);       // region B: [nb1, 40), capped
    #pragma unroll
    for (int j = 0; j < 32; ++j) {
        const bool a = (maskA >> j) & 1u;
        const bool b = (maskB >> j) & 1u;
        const int  dst = a ? baseA : baseB;
        if ((a | b) && (a || baseB < KNB))
            cp[dst] = lane + (j << 6);
        baseA += (int)a;
        baseB += (int)b;
    }
    return true;
}

// rebuild_fb: rare fallback — re-derive d2, bins at [0,1024) width 4, re-hist.
static __device__ __forceinline__ void rebuild_fb(
    const float4* __restrict__ cb4, const float cvx, const float cvy,
    const float cvz, const float cvw, const int jself,
    const int lself, int* __restrict__ hw, unsigned int (&binsW)[8][64],
    unsigned int& nearm, const int lane)
{
    const int4 izero = {0, 0, 0, 0};
    ((int4*)hw)[lane] = izero;
    nearm = 0u;
    #pragma unroll
    for (int q = 0; q < 8; ++q) {
        unsigned int wq = 0u;
        #pragma unroll
        for (int t = 0; t < 4; ++t) {
            const int j = q * 4 + t;       // compile-time constant
            const float4 cw = cb4[lane + (j << 6)];
            const float dx = cvx - cw.x, dy = cvy - cw.y;
            const float dz = cvz - cw.z, dw = cvw - cw.w;
            float d2 = dx*dx + dy*dy + dz*dz + dw*dw;
            if (j == jself && lane == lself) d2 = FLT_MAX;
            const bool nr = (d2 < 1024.f);
            const int  bb = nr ? (int)(d2 * 0.25f) : 255;
            wq    |= (unsigned int)bb << (t * 8);
            nearm |= (nr ? 1u : 0u) << j;
            if (nr) atomicAdd(&hw[bb], 1);
        }
        binsW[q][lane] = wq;               // conflict-free ds_write_b32
        if (q & 1) __builtin_amdgcn_sched_barrier(0); // cap in-flight loads
    }
}

// ---------------------------------------------------------------------------
// Kernel 2: k_knn — FUSED select + pool, ONE row per wave.
// R12: R11's lean select (VGPR 52, no spill, occ 43%) hit VALUBusy 88% —
// VALU-issue-bound, residency lever exhausted. But the select+pool SPLIT
// now loses overall (select 181 + pool 31 + idx roundtrip + extra launch >
// R6's fused 162). Re-fuse: select phase is VALU-bound, pool phase is
// gather-bound — complementary pipes, fused time ~ max not sum across
// resident waves. Pool transients (fv[20] + SGPR readlane idx/wgt) fit
// under the select phase's own 52-reg peak. Also: bins LDS transposed
// [8][64] (conflict-free; was 16-way, 11.3M conflicts). Select semantics
// byte-identical to passing R4-R11.
// ---------------------------------------------------------------------------
__global__ __launch_bounds__(256) void k_knn(
    const float* __restrict__ coords, const float* __restrict__ feats,
    float* __restrict__ collected)
{
    __shared__ int hist[4][256];               // 4 KB (per-wave)
    __shared__ int candP[4][KNB];              // 640 B: neighbor idx
    __shared__ unsigned int binsT[4][8][64];   // 8 KB: transposed bins

    const int tid   = threadIdx.x;
    const int lane  = tid & 63;
    const int w     = tid >> 6;
    // XCD swizzle: 16384 blocks, 8 XCDs -> 2048 contiguous blocks per XCD.
    const int bid   = (int)blockIdx.x;
    const int swz   = ((bid & 7) << 11) + (bid >> 3);
    // one row per wave (wave-uniform)
    const int vu    = __builtin_amdgcn_readfirstlane((swz << 2) + w);
    const int batch = vu >> 11;
    const int vloc  = vu & (VV - 1);
    const float4* cb4 = (const float4*)(coords + (size_t)batch * VV * DD);
    const float*  fb  = feats + (size_t)batch * VV * PP;

    const int4 izero = {0, 0, 0, 0};

    // query coords -> SGPRs (uniform)
    const float4 cvv = cb4[vloc];
    const float cvx = rfl_f(cvv.x), cvy = rfl_f(cvv.y);
    const float cvz = rfl_f(cvv.z), cvw = rfl_f(cvv.w);
    const int jself = vloc >> 6;
    const int lself = vloc & 63;

    ((int4*)hist[w])[lane] = izero;

    // ---- fused distance + bin-pack(->LDS) + histogram ----
    unsigned int nearm = 0u;
    #pragma unroll
    for (int q = 0; q < 8; ++q) {
        unsigned int wq = 0u;
        #pragma unroll
        for (int t = 0; t < 4; ++t) {
            const int j = q * 4 + t;       // compile-time constant
            const float4 cw = cb4[lane + (j << 6)];
            const float dx = cvx - cw.x, dy = cvy - cw.y;
            const float dz = cvz - cw.z, dw = cvw - cw.w;
            float d2 = dx*dx + dy*dy + dz*dz + dw*dw;
            if (j == jself && lane == lself) d2 = FLT_MAX;  // self -> sentinel
            const bool nr = (d2 < 4.f);
            const int  bb = nr ? (int)(d2 * 64.f) : 255;
            wq    |= (unsigned int)bb << (t * 8);
            nearm |= (nr ? 1u : 0u) << j;
            if (nr) atomicAdd(&hist[w][bb], 1);
        }
        binsT[w][q][lane] = wq;            // conflict-free ds_write_b32
        if (q & 1) __builtin_amdgcn_sched_barrier(0); // cap in-flight loads
    }

    // ---- select + collect (fallback rare, wave-uniform) ----
    if (!select_collect(binsT[w], nearm, hist[w], candP[w], lane, true)) {
        rebuild_fb(cb4, cvx, cvy, cvz, cvw, jself, lself,
                   hist[w], binsT[w], nearm, lane);
        select_collect(binsT[w], nearm, hist[w], candP[w], lane, false);
    }

    // ---- weights+indices into lane registers (lanes 0..39) ----
    int ireg = 0; float wgt = 0.f;
    if (lane < KNB) {
        ireg = candP[w][lane];                       // ds_read (in-order)
        const float4 cw = cb4[ireg];                 // gather
        const float dx = cvx - cw.x, dy = cvy - cw.y;
        const float dz = cvz - cw.z, dw = cvw - cw.w;
        wgt = __expf(-10.f * (dx*dx + dy*dy + dz*dz + dw*dw));
    }

    // ---- pool 40 neighbors: readlane -> SGPR idx/weight, saddr gathers ----
    float mx = -FLT_MAX, sm = 0.f;
    #pragma unroll
    for (int j0 = 0; j0 < KNB; j0 += 20) {
        float fv[20]; float wv[20];
        #pragma unroll
        for (int t = 0; t < 20; ++t) {
            const int si = __builtin_amdgcn_readlane(ireg, j0 + t);   // SGPR
            wv[t] = __uint_as_float(
                (unsigned int)__builtin_amdgcn_readlane(__float_as_int(wgt), j0 + t));
            fv[t] = fb[(size_t)(si * PP) + lane];                     // saddr
        }
        #pragma unroll
        for (int t = 0; t < 20; ++t) {
            const float nv = fv[t] * wv[t];
            mx = fmaxf(mx, nv);
            sm += nv;
        }
    }
    float* rowp = collected + ((size_t)vu << 7);
    rowp[lane]      = mx;
    rowp[PP + lane] = sm * (1.f / KNB);
}

// ---------------------------------------------------------------------------
// Kernel 3: out = tanh(concat(x, collected) @ W_out + b_out), (N x 192)@(192 x 128)
// (unchanged, passing)
// ---------------------------------------------------------------------------
__global__ __launch_bounds__(256) void k_out(
    const float* __restrict__ x, const float* __restrict__ collected,
    const float* __restrict__ Wout, const float* __restrict__ bout,
    float* __restrict__ out)
{
    __shared__ float As[16][68];   // [kk][r], +4 pad
    __shared__ float Bs[16][128];
    const int tid = threadIdx.x;
    const int tx  = tid & 15;
    const int ty  = tid >> 4;
    const int row0 = blockIdx.x * 64;

    float acc[4][8];
    #pragma unroll
    for (int i = 0; i < 4; ++i)
        #pragma unroll
        for (int j = 0; j < 8; ++j) acc[i][j] = 0.f;

    for (int k0 = 0; k0 < 192; k0 += 16) {
        {   // stage A tile transposed: thread loads (r, kk4..kk4+3), scatters
            const int r   = tid >> 2;
            const int kk4 = (tid & 3) << 2;
            const float* src = (k0 < 64)
                ? (x + (size_t)(row0 + r) * FIN + (k0 + kk4))
                : (collected + (size_t)(row0 + r) * 128 + (k0 - 64 + kk4));
            float4 v = *(const float4*)src;
            As[kk4+0][r] = v.x; As[kk4+1][r] = v.y;
            As[kk4+2][r] = v.z; As[kk4+3][r] = v.w;
        }
        #pragma unroll
        for (int rep = 0; rep < 2; ++rep) {
            const int e = (tid + rep * 256) * 4;
            const int kk = e >> 7, c = e & 127;
            *(float4*)&Bs[kk][c] = *(const float4*)(Wout + (size_t)(k0 + kk) * 128 + c);
        }
        __syncthreads();
        #pragma unroll
        for (int kk = 0; kk < 16; ++kk) {
            float4 a  = *(const float4*)&As[kk][ty * 4];
            float4 b0 = *(const float4*)&Bs[kk][tx * 4];
            float4 b1 = *(const float4*)&Bs[kk][64 + tx * 4];
            const float av[4] = {a.x, a.y, a.z, a.w};
            #pragma unroll
            for (int i = 0; i < 4; ++i) {
                acc[i][0] += av[i] * b0.x; acc[i][1] += av[i] * b0.y;
                acc[i][2] += av[i] * b0.z; acc[i][3] += av[i] * b0.w;
                acc[i][4] += av[i] * b1.x; acc[i][5] += av[i] * b1.y;
                acc[i][6] += av[i] * b1.z; acc[i][7] += av[i] * b1.w;
            }
        }
        __syncthreads();
    }

    #pragma unroll
    for (int i = 0; i < 4; ++i) {
        const int row = row0 + ty * 4 + i;
        float4 o0, o1;
        o0.x = fast_tanh(acc[i][0] + bout[tx*4+0]);
        o0.y = fast_tanh(acc[i][1] + bout[tx*4+1]);
        o0.z = fast_tanh(acc[i][2] + bout[tx*4+2]);
        o0.w = fast_tanh(acc[i][3] + bout[tx*4+3]);
        o1.x = fast_tanh(acc[i][4] + bout[64+tx*4+0]);
        o1.y = fast_tanh(acc[i][5] + bout[64+tx*4+1]);
        o1.z = fast_tanh(acc[i][6] + bout[64+tx*4+2]);
        o1.w = fast_tanh(acc[i][7] + bout[64+tx*4+3]);
        *(float4*)(out + (size_t)row * 128 + tx * 4)      = o0;
        *(float4*)(out + (size_t)row * 128 + 64 + tx * 4) = o1;
    }
}

// ---------------------------------------------------------------------------
extern "C" void kernel_launch(void* const* d_in, const int* in_sizes, int n_in,
                              void* d_out, int out_size, void* d_ws, size_t ws_size,
                              hipStream_t stream)
{
    const float* x    = (const float*)d_in[0];
    // d_in[1] = row_splits: uniform arange(B+1)*V — fixed structure, unused.
    const float* Ws   = (const float*)d_in[2];
    const float* bs   = (const float*)d_in[3];
    const float* Wf   = (const float*)d_in[4];
    const float* bf   = (const float*)d_in[5];
    const float* Wout = (const float*)d_in[6];
    const float* bout = (const float*)d_in[7];
    float* out = (float*)d_out;

    float* coords = (float*)d_ws;                                            // 1 MB
    float* feats  = (float*)((char*)d_ws + (size_t)NN * DD * sizeof(float)); // 16 MB
    float* collected = out;   // reuse d_out as scratch for pooled features

    hipLaunchKernelGGL(k_embed, dim3(NN / 64), dim3(256), 0, stream,
                       x, Ws, bs, Wf, bf, coords, feats);
    // fused select+pool: 1 row per wave, 4 waves/block -> 16384 blocks
    hipLaunchKernelGGL(k_knn, dim3(NN / 4), dim3(256), 0, stream,
                       coords, feats, collected);
    hipLaunchKernelGGL(k_out, dim3(NN / 64), dim3(256), 0, stream,
                       x, collected, Wout, bout, out);
}

// Round 13
// 285.083 us; speedup vs baseline: 1.6411x; 1.1378x over previous
//
#include <hip/hip_runtime.h>
#include <cfloat>

#define BB   32
#define VV   2048
#define KNB  40
#define FIN  64
#define DD   4
#define PP   64
#define NN   (BB*VV)           // 65536

static __device__ __forceinline__ float fast_tanh(float z) {
    z = fminf(fmaxf(z, -15.f), 15.f);
    float e = __expf(2.f * z);
    return (e - 1.f) / (e + 1.f);
}

static __device__ __forceinline__ float rfl_f(float x) {
    return __uint_as_float(
        (unsigned)__builtin_amdgcn_readfirstlane(__float_as_int(x)));
}

// Wave64 inclusive add-scan via DPP (rocPRIM pattern): 6 VALU ops, no DS pipe.
static __device__ __forceinline__ int wave_incl_scan(int x) {
    x += __builtin_amdgcn_update_dpp(0, x, 0x111, 0xf, 0xf, true); // row_shr:1
    x += __builtin_amdgcn_update_dpp(0, x, 0x112, 0xf, 0xf, true); // row_shr:2
    x += __builtin_amdgcn_update_dpp(0, x, 0x114, 0xf, 0xf, true); // row_shr:4
    x += __builtin_amdgcn_update_dpp(0, x, 0x118, 0xf, 0xf, true); // row_shr:8
    x += __builtin_amdgcn_update_dpp(0, x, 0x142, 0xa, 0xf, true); // row_bcast:15 -> rows 1,3
    x += __builtin_amdgcn_update_dpp(0, x, 0x143, 0xc, 0xf, true); // row_bcast:31 -> rows 2,3
    return x;
}

// ---------------------------------------------------------------------------
// Kernel 1: coords = x@W_s + b_s (N x 4), feats = x@W_f + b_f (N x 64)
// (unchanged, passing)
// ---------------------------------------------------------------------------
__global__ __launch_bounds__(256) void k_embed(
    const float* __restrict__ x, const float* __restrict__ Ws,
    const float* __restrict__ bs, const float* __restrict__ Wf,
    const float* __restrict__ bf, float* __restrict__ coords,
    float* __restrict__ feats)
{
    __shared__ float Xs[64][68];
    __shared__ float Wfs[64][64];
    __shared__ float Wss[64][4];
    const int tid  = threadIdx.x;
    const int row0 = blockIdx.x * 64;

    #pragma unroll
    for (int i = 0; i < 4; ++i) {
        const int idx = tid + i * 256;
        const int r   = idx >> 4;
        const int k4  = (idx & 15) << 2;
        float4 v = *(const float4*)(x + (size_t)(row0 + r) * FIN + k4);
        Xs[k4+0][r] = v.x; Xs[k4+1][r] = v.y; Xs[k4+2][r] = v.z; Xs[k4+3][r] = v.w;
        ((float4*)Wfs)[idx] = ((const float4*)Wf)[idx];
    }
    if (tid < 64) *(float4*)Wss[tid] = ((const float4*)Ws)[tid];
    __syncthreads();

    const int tx = tid & 15;
    const int ty = tid >> 4;
    float acc[4][4] = {};
    #pragma unroll 16
    for (int k = 0; k < 64; ++k) {
        float4 a = *(const float4*)&Xs[k][ty * 4];
        float4 b = *(const float4*)&Wfs[k][tx * 4];
        acc[0][0] += a.x*b.x; acc[0][1] += a.x*b.y; acc[0][2] += a.x*b.z; acc[0][3] += a.x*b.w;
        acc[1][0] += a.y*b.x; acc[1][1] += a.y*b.y; acc[1][2] += a.y*b.z; acc[1][3] += a.y*b.w;
        acc[2][0] += a.z*b.x; acc[2][1] += a.z*b.y; acc[2][2] += a.z*b.z; acc[2][3] += a.z*b.w;
        acc[3][0] += a.w*b.x; acc[3][1] += a.w*b.y; acc[3][2] += a.w*b.z; acc[3][3] += a.w*b.w;
    }
    const float4 bfv = *(const float4*)(bf + tx * 4);
    const float ar[4] = {bfv.x, bfv.y, bfv.z, bfv.w};
    #pragma unroll
    for (int i = 0; i < 4; ++i) {
        float4 o = { acc[i][0] + ar[0], acc[i][1] + ar[1],
                     acc[i][2] + ar[2], acc[i][3] + ar[3] };
        *(float4*)(feats + (size_t)(row0 + ty * 4 + i) * PP + tx * 4) = o;
    }

    const int cr = tid >> 2, cc = tid & 3;
    float ca = bs[cc];
    #pragma unroll 16
    for (int k = 0; k < 64; ++k) ca += Xs[k][cr] * Wss[k][cc];
    coords[(size_t)(row0 + cr) * DD + cc] = ca;
}

// ---------------------------------------------------------------------------
// select_collect: bins in per-wave transposed LDS binsW[8][64] (lane-major,
// conflict-free). Selection semantics EXACTLY the float-compare select of
// R4-R12:
//   bin < g1         <=>  d2 < g1/scale  (exact pow2 scale)
//   bin == g1 & near <=>  d2 in boundary bin (far/self have near=0).
// R13: scatter is ffs-while over set bits (avg ~1.2/lane vs 32 static
// iters). Destinations identical: ascending-j per lane, same scan bases.
// Returns false (before collecting) if total < KNB and allow_fail.
// ---------------------------------------------------------------------------
static __device__ __forceinline__ bool select_collect(
    const unsigned int (&binsW)[8][64], const unsigned int nearmask,
    int* __restrict__ hw, int* __restrict__ cp, const int lane,
    const bool allow_fail)
{
    int4 hv = ((const int4*)hw)[lane];
    const int local = hv.x + hv.y + hv.z + hv.w;
    const int incl  = wave_incl_scan(local);
    if (allow_fail) {
        const int total = __builtin_amdgcn_readlane(incl, 63);
        if (total < KNB) return false;
    }
    const int excl = incl - local;
    const bool pred = (excl < KNB) && (incl >= KNB);
    const unsigned long long m = __ballot(pred);
    const int src = (m == 0ull) ? 0 : ((int)__ffsll(m) - 1);  // uniform
    int gg = 0, nnb = 0;
    if (pred) {
        const int hh[4] = {hv.x, hv.y, hv.z, hv.w};
        int cacc = excl, found = -1;
        #pragma unroll
        for (int q = 0; q < 4; ++q) {
            if (found < 0 && cacc + hh[q] >= KNB) { found = q; nnb = cacc; }
            cacc += hh[q];
        }
        gg = (lane << 2) + found;
    }
    const int g1  = __builtin_amdgcn_readlane(gg,  src);
    const int nb1 = __builtin_amdgcn_readlane(nnb, src);

    // ---- bins back from LDS (8x conflict-free ds_read_b32, transient) ----
    unsigned int bw[8];
    #pragma unroll
    for (int q = 0; q < 8; ++q) bw[q] = binsW[q][lane];

    // ---- masks from bin bytes (bfe + cmp; no floats) ----
    unsigned int maskA = 0u, maskB = 0u;
    #pragma unroll
    for (int j = 0; j < 32; ++j) {
        const int bb = (int)((bw[j >> 2] >> ((j & 3) * 8)) & 255u);
        if (bb < g1) maskA |= (1u << j);
        else if (bb == g1) maskB |= (1u << j);
    }
    maskB &= nearmask;                     // drop far/self sentinels (bin 255)

    const int packed = __popc(maskA) | (__popc(maskB) << 16);
    const int incl2  = wave_incl_scan(packed);
    const int excl2  = incl2 - packed;
    int baseA = excl2 & 0xFFFF;            // region A: [0, nb1)
    int baseB = nb1 + (excl2 >> 16);       // region B: [nb1, 40), capped
    while (maskA) {                        // ascending j: identical dsts
        const int j = __ffs(maskA) - 1; maskA &= maskA - 1;
        cp[baseA++] = lane + (j << 6);
    }
    while (maskB && baseB < KNB) {
        const int j = __ffs(maskB) - 1; maskB &= maskB - 1;
        cp[baseB++] = lane + (j << 6);
    }
    return true;
}

// rebuild_fb: rare fallback — re-derive d2, bins at [0,1024) width 4, re-hist.
static __device__ __forceinline__ void rebuild_fb(
    const float4* __restrict__ cb4, const float cvx, const float cvy,
    const float cvz, const float cvw, const int jself,
    const int lself, int* __restrict__ hw, unsigned int (&binsW)[8][64],
    unsigned int& nearm, const int lane)
{
    const int4 izero = {0, 0, 0, 0};
    ((int4*)hw)[lane] = izero;
    nearm = 0u;
    #pragma unroll
    for (int q = 0; q < 8; ++q) {
        unsigned int wq = 0u;
        #pragma unroll
        for (int t = 0; t < 4; ++t) {
            const int j = q * 4 + t;       // compile-time constant
            const float4 cw = cb4[lane + (j << 6)];
            const float dx = cvx - cw.x, dy = cvy - cw.y;
            const float dz = cvz - cw.z, dw = cvw - cw.w;
            float d2 = dx*dx + dy*dy + dz*dz + dw*dw;
            if (j == jself && lane == lself) d2 = FLT_MAX;
            const bool nr = (d2 < 1024.f);
            const int  bb = nr ? (int)(d2 * 0.25f) : 255;
            wq    |= (unsigned int)bb << (t * 8);
            nearm |= (nr ? 1u : 0u) << j;
            if (nr) atomicAdd(&hw[bb], 1);
        }
        binsW[q][lane] = wq;               // conflict-free ds_write_b32
        __builtin_amdgcn_sched_barrier(0); // cap in-flight loads
    }
}

// ---------------------------------------------------------------------------
// Kernel 2: k_knn — FUSED select + pool, TWO rows per wave.
// R13: R12 is VALU-issue-bound (VALUBusy 98%) and its 1-row chain showed
// select+pool times ADD (197.6 = 181.5 + 16) — no in-wave overlap. 2-row
// ILP (R6's proven lever, 193->162 even WITH spill) now fits without spill
// because bins live in LDS (R12: VGPR 44; dual-row state ~ +12). One
// distance loop loads each cw ONCE for both rows; the two select chains'
// serial DS latencies interleave; pools run back-to-back reusing the same
// transient window. Scatter = ffs-while (identical dsts, ~1.2 vs 32 iters).
// Select semantics byte-identical to passing R4-R12.
// Go/no-go signature: VGPR <= 64, no spill (WRITE ~32.8MB only).
// ---------------------------------------------------------------------------
__global__ __launch_bounds__(256) void k_knn(
    const float* __restrict__ coords, const float* __restrict__ feats,
    float* __restrict__ collected)
{
    __shared__ int hist[4][2][256];              // 8 KB (per-wave x 2 rows)
    __shared__ int candP[4][2][KNB];             // 1.25 KB: neighbor idx
    __shared__ unsigned int binsT[4][2][8][64];  // 16 KB: transposed bins

    const int tid   = threadIdx.x;
    const int lane  = tid & 63;
    const int w     = tid >> 6;
    // XCD swizzle: 8192 blocks, 8 XCDs -> 1024 contiguous blocks per XCD.
    const int bid   = (int)blockIdx.x;
    const int swz   = ((bid & 7) << 10) + (bid >> 3);
    // two rows per wave: vA even, vB = vA+1 (both wave-uniform)
    const int vA    = __builtin_amdgcn_readfirstlane((swz << 3) + (w << 1));
    const int vB    = vA + 1;
    const int batch = vA >> 11;
    const int vlocA = vA & (VV - 1);
    const float4* cb4 = (const float4*)(coords + (size_t)batch * VV * DD);
    const float*  fb  = feats + (size_t)batch * VV * PP;

    const int4 izero = {0, 0, 0, 0};

    // query coords -> SGPRs (uniform)
    const float4 cva = cb4[vlocA];
    const float4 cvb = cb4[vlocA + 1];
    const float cax = rfl_f(cva.x), cay = rfl_f(cva.y);
    const float caz = rfl_f(cva.z), caw = rfl_f(cva.w);
    const float cbx = rfl_f(cvb.x), cby = rfl_f(cvb.y);
    const float cbz = rfl_f(cvb.z), cbw = rfl_f(cvb.w);
    const int jself  = vlocA >> 6;         // == (vlocA+1)>>6 (vA even)
    const int lselfA = vlocA & 63;
    const int lselfB = lselfA + 1;

    ((int4*)hist[w][0])[lane] = izero;
    ((int4*)hist[w][1])[lane] = izero;

    // ---- fused distance + bin-pack(->LDS) + histogram, BOTH rows ----
    unsigned int nearA = 0u, nearB = 0u;
    #pragma unroll
    for (int q = 0; q < 8; ++q) {
        unsigned int wqA = 0u, wqB = 0u;
        #pragma unroll
        for (int t = 0; t < 4; ++t) {
            const int j = q * 4 + t;       // compile-time constant
            const float4 cw = cb4[lane + (j << 6)];
            const float dxA = cax - cw.x, dyA = cay - cw.y;
            const float dzA = caz - cw.z, dwA = caw - cw.w;
            float d2A = dxA*dxA + dyA*dyA + dzA*dzA + dwA*dwA;
            const float dxB = cbx - cw.x, dyB = cby - cw.y;
            const float dzB = cbz - cw.z, dwB = cbw - cw.w;
            float d2B = dxB*dxB + dyB*dyB + dzB*dzB + dwB*dwB;
            if (j == jself) {              // uniform scalar branch
                if (lane == lselfA) d2A = FLT_MAX;
                if (lane == lselfB) d2B = FLT_MAX;
            }
            const bool nA = (d2A < 4.f), nB = (d2B < 4.f);
            const int  bA = nA ? (int)(d2A * 64.f) : 255;
            const int  bB = nB ? (int)(d2B * 64.f) : 255;
            wqA   |= (unsigned int)bA << (t * 8);
            wqB   |= (unsigned int)bB << (t * 8);
            nearA |= (nA ? 1u : 0u) << j;
            nearB |= (nB ? 1u : 0u) << j;
            if (nA) atomicAdd(&hist[w][0][bA], 1);
            if (nB) atomicAdd(&hist[w][1][bB], 1);
        }
        binsT[w][0][q][lane] = wqA;        // conflict-free ds_write_b32
        binsT[w][1][q][lane] = wqB;
        __builtin_amdgcn_sched_barrier(0); // cap in-flight loads per chunk
    }

    // ---- per-row select + collect (fallback rare, wave-uniform) ----
    if (!select_collect(binsT[w][0], nearA, hist[w][0], candP[w][0], lane, true)) {
        rebuild_fb(cb4, cax, cay, caz, caw, jself, lselfA,
                   hist[w][0], binsT[w][0], nearA, lane);
        select_collect(binsT[w][0], nearA, hist[w][0], candP[w][0], lane, false);
    }
    if (!select_collect(binsT[w][1], nearB, hist[w][1], candP[w][1], lane, true)) {
        rebuild_fb(cb4, cbx, cby, cbz, cbw, jself, lselfB,
                   hist[w][1], binsT[w][1], nearB, lane);
        select_collect(binsT[w][1], nearB, hist[w][1], candP[w][1], lane, false);
    }

    // ---- pools, sequential (reuse the same transient window) ----
    #pragma unroll
    for (int r = 0; r < 2; ++r) {
        const float qx = r ? cbx : cax, qy = r ? cby : cay;
        const float qz = r ? cbz : caz, qw = r ? cbw : caw;
        int ireg = 0; float wgt = 0.f;
        if (lane < KNB) {
            ireg = candP[w][r][lane];                // ds_read (in-order)
            const float4 cw = cb4[ireg];             // gather
            const float dx = qx - cw.x, dy = qy - cw.y;
            const float dz = qz - cw.z, dw = qw - cw.w;
            wgt = __expf(-10.f * (dx*dx + dy*dy + dz*dz + dw*dw));
        }
        float mx = -FLT_MAX, sm = 0.f;
        #pragma unroll
        for (int j0 = 0; j0 < KNB; j0 += 20) {
            float fv[20]; float wv[20];
            #pragma unroll
            for (int t = 0; t < 20; ++t) {
                const int si = __builtin_amdgcn_readlane(ireg, j0 + t);   // SGPR
                wv[t] = __uint_as_float(
                    (unsigned int)__builtin_amdgcn_readlane(__float_as_int(wgt), j0 + t));
                fv[t] = fb[(size_t)(si * PP) + lane];                     // saddr
            }
            #pragma unroll
            for (int t = 0; t < 20; ++t) {
                const float nv = fv[t] * wv[t];
                mx = fmaxf(mx, nv);
                sm += nv;
            }
        }
        float* rowp = collected + ((size_t)(vA + r) << 7);
        rowp[lane]      = mx;
        rowp[PP + lane] = sm * (1.f / KNB);
    }
}

// ---------------------------------------------------------------------------
// Kernel 3: out = tanh(concat(x, collected) @ W_out + b_out), (N x 192)@(192 x 128)
// (unchanged, passing)
// ---------------------------------------------------------------------------
__global__ __launch_bounds__(256) void k_out(
    const float* __restrict__ x, const float* __restrict__ collected,
    const float* __restrict__ Wout, const float* __restrict__ bout,
    float* __restrict__ out)
{
    __shared__ float As[16][68];   // [kk][r], +4 pad
    __shared__ float Bs[16][128];
    const int tid = threadIdx.x;
    const int tx  = tid & 15;
    const int ty  = tid >> 4;
    const int row0 = blockIdx.x * 64;

    float acc[4][8];
    #pragma unroll
    for (int i = 0; i < 4; ++i)
        #pragma unroll
        for (int j = 0; j < 8; ++j) acc[i][j] = 0.f;

    for (int k0 = 0; k0 < 192; k0 += 16) {
        {   // stage A tile transposed: thread loads (r, kk4..kk4+3), scatters
            const int r   = tid >> 2;
            const int kk4 = (tid & 3) << 2;
            const float* src = (k0 < 64)
                ? (x + (size_t)(row0 + r) * FIN + (k0 + kk4))
                : (collected + (size_t)(row0 + r) * 128 + (k0 - 64 + kk4));
            float4 v = *(const float4*)src;
            As[kk4+0][r] = v.x; As[kk4+1][r] = v.y;
            As[kk4+2][r] = v.z; As[kk4+3][r] = v.w;
        }
        #pragma unroll
        for (int rep = 0; rep < 2; ++rep) {
            const int e = (tid + rep * 256) * 4;
            const int kk = e >> 7, c = e & 127;
            *(float4*)&Bs[kk][c] = *(const float4*)(Wout + (size_t)(k0 + kk) * 128 + c);
        }
        __syncthreads();
        #pragma unroll
        for (int kk = 0; kk < 16; ++kk) {
            float4 a  = *(const float4*)&As[kk][ty * 4];
            float4 b0 = *(const float4*)&Bs[kk][tx * 4];
            float4 b1 = *(const float4*)&Bs[kk][64 + tx * 4];
            const float av[4] = {a.x, a.y, a.z, a.w};
            #pragma unroll
            for (int i = 0; i < 4; ++i) {
                acc[i][0] += av[i] * b0.x; acc[i][1] += av[i] * b0.y;
                acc[i][2] += av[i] * b0.z; acc[i][3] += av[i] * b0.w;
                acc[i][4] += av[i] * b1.x; acc[i][5] += av[i] * b1.y;
                acc[i][6] += av[i] * b1.z; acc[i][7] += av[i] * b1.w;
            }
        }
        __syncthreads();
    }

    #pragma unroll
    for (int i = 0; i < 4; ++i) {
        const int row = row0 + ty * 4 + i;
        float4 o0, o1;
        o0.x = fast_tanh(acc[i][0] + bout[tx*4+0]);
        o0.y = fast_tanh(acc[i][1] + bout[tx*4+1]);
        o0.z = fast_tanh(acc[i][2] + bout[tx*4+2]);
        o0.w = fast_tanh(acc[i][3] + bout[tx*4+3]);
        o1.x = fast_tanh(acc[i][4] + bout[64+tx*4+0]);
        o1.y = fast_tanh(acc[i][5] + bout[64+tx*4+1]);
        o1.z = fast_tanh(acc[i][6] + bout[64+tx*4+2]);
        o1.w = fast_tanh(acc[i][7] + bout[64+tx*4+3]);
        *(float4*)(out + (size_t)row * 128 + tx * 4)      = o0;
        *(float4*)(out + (size_t)row * 128 + 64 + tx * 4) = o1;
    }
}

// ---------------------------------------------------------------------------
extern "C" void kernel_launch(void* const* d_in, const int* in_sizes, int n_in,
                              void* d_out, int out_size, void* d_ws, size_t ws_size,
                              hipStream_t stream)
{
    const float* x    = (const float*)d_in[0];
    // d_in[1] = row_splits: uniform arange(B+1)*V — fixed structure, unused.
    const float* Ws   = (const float*)d_in[2];
    const float* bs   = (const float*)d_in[3];
    const float* Wf   = (const float*)d_in[4];
    const float* bf   = (const float*)d_in[5];
    const float* Wout = (const float*)d_in[6];
    const float* bout = (const float*)d_in[7];
    float* out = (float*)d_out;

    float* coords = (float*)d_ws;                                            // 1 MB
    float* feats  = (float*)((char*)d_ws + (size_t)NN * DD * sizeof(float)); // 16 MB
    float* collected = out;   // reuse d_out as scratch for pooled features

    hipLaunchKernelGGL(k_embed, dim3(NN / 64), dim3(256), 0, stream,
                       x, Ws, bs, Wf, bf, coords, feats);
    // fused select+pool: 2 rows per wave, 4 waves/block -> 8192 blocks
    hipLaunchKernelGGL(k_knn, dim3(NN / 8), dim3(256), 0, stream,
                       coords, feats, collected);
    hipLaunchKernelGGL(k_out, dim3(NN / 64), dim3(256), 0, stream,
                       x, collected, Wout, bout, out);
}

// Round 14
// 248.918 us; speedup vs baseline: 1.8796x; 1.1453x over previous
//
#include <hip/hip_runtime.h>
#include <cfloat>

#define BB   32
#define VV   2048
#define KNB  40
#define FIN  64
#define DD   4
#define PP   64
#define NN   (BB*VV)           // 65536

typedef __attribute__((ext_vector_type(8))) short bf16x8;
typedef __attribute__((ext_vector_type(4))) float f32x4;

static __device__ __forceinline__ float fast_tanh(float z) {
    z = fminf(fmaxf(z, -15.f), 15.f);
    float e = __expf(2.f * z);
    return (e - 1.f) / (e + 1.f);
}

static __device__ __forceinline__ float rfl_f(float x) {
    return __uint_as_float(
        (unsigned)__builtin_amdgcn_readfirstlane(__float_as_int(x)));
}

// float -> bf16 bits, round-to-nearest-even
static __device__ __forceinline__ unsigned int bf16rne(float f) {
    const unsigned int u = __float_as_uint(f);
    return (u + 0x7FFFu + ((u >> 16) & 1u)) >> 16;
}

// Wave64 inclusive add-scan via DPP (rocPRIM pattern): 6 VALU ops, no DS pipe.
static __device__ __forceinline__ int wave_incl_scan(int x) {
    x += __builtin_amdgcn_update_dpp(0, x, 0x111, 0xf, 0xf, true); // row_shr:1
    x += __builtin_amdgcn_update_dpp(0, x, 0x112, 0xf, 0xf, true); // row_shr:2
    x += __builtin_amdgcn_update_dpp(0, x, 0x114, 0xf, 0xf, true); // row_shr:4
    x += __builtin_amdgcn_update_dpp(0, x, 0x118, 0xf, 0xf, true); // row_shr:8
    x += __builtin_amdgcn_update_dpp(0, x, 0x142, 0xa, 0xf, true); // row_bcast:15 -> rows 1,3
    x += __builtin_amdgcn_update_dpp(0, x, 0x143, 0xc, 0xf, true); // row_bcast:31 -> rows 2,3
    return x;
}

// ---------------------------------------------------------------------------
// Kernel 1: coords = x@W_s + b_s (N x 4), feats = x@W_f + b_f (N x 64)
// (unchanged, passing)
// ---------------------------------------------------------------------------
__global__ __launch_bounds__(256) void k_embed(
    const float* __restrict__ x, const float* __restrict__ Ws,
    const float* __restrict__ bs, const float* __restrict__ Wf,
    const float* __restrict__ bf, float* __restrict__ coords,
    float* __restrict__ feats)
{
    __shared__ float Xs[64][68];
    __shared__ float Wfs[64][64];
    __shared__ float Wss[64][4];
    const int tid  = threadIdx.x;
    const int row0 = blockIdx.x * 64;

    #pragma unroll
    for (int i = 0; i < 4; ++i) {
        const int idx = tid + i * 256;
        const int r   = idx >> 4;
        const int k4  = (idx & 15) << 2;
        float4 v = *(const float4*)(x + (size_t)(row0 + r) * FIN + k4);
        Xs[k4+0][r] = v.x; Xs[k4+1][r] = v.y; Xs[k4+2][r] = v.z; Xs[k4+3][r] = v.w;
        ((float4*)Wfs)[idx] = ((const float4*)Wf)[idx];
    }
    if (tid < 64) *(float4*)Wss[tid] = ((const float4*)Ws)[tid];
    __syncthreads();

    const int tx = tid & 15;
    const int ty = tid >> 4;
    float acc[4][4] = {};
    #pragma unroll 16
    for (int k = 0; k < 64; ++k) {
        float4 a = *(const float4*)&Xs[k][ty * 4];
        float4 b = *(const float4*)&Wfs[k][tx * 4];
        acc[0][0] += a.x*b.x; acc[0][1] += a.x*b.y; acc[0][2] += a.x*b.z; acc[0][3] += a.x*b.w;
        acc[1][0] += a.y*b.x; acc[1][1] += a.y*b.y; acc[1][2] += a.y*b.z; acc[1][3] += a.y*b.w;
        acc[2][0] += a.z*b.x; acc[2][1] += a.z*b.y; acc[2][2] += a.z*b.z; acc[2][3] += a.z*b.w;
        acc[3][0] += a.w*b.x; acc[3][1] += a.w*b.y; acc[3][2] += a.w*b.z; acc[3][3] += a.w*b.w;
    }
    const float4 bfv = *(const float4*)(bf + tx * 4);
    const float ar[4] = {bfv.x, bfv.y, bfv.z, bfv.w};
    #pragma unroll
    for (int i = 0; i < 4; ++i) {
        float4 o = { acc[i][0] + ar[0], acc[i][1] + ar[1],
                     acc[i][2] + ar[2], acc[i][3] + ar[3] };
        *(float4*)(feats + (size_t)(row0 + ty * 4 + i) * PP + tx * 4) = o;
    }

    const int cr = tid >> 2, cc = tid & 3;
    float ca = bs[cc];
    #pragma unroll 16
    for (int k = 0; k < 64; ++k) ca += Xs[k][cr] * Wss[k][cc];
    coords[(size_t)(row0 + cr) * DD + cc] = ca;
}

// ---------------------------------------------------------------------------
// select_collect (unchanged from R13, passing)
// ---------------------------------------------------------------------------
static __device__ __forceinline__ bool select_collect(
    const unsigned int (&binsW)[8][64], const unsigned int nearmask,
    int* __restrict__ hw, int* __restrict__ cp, const int lane,
    const bool allow_fail)
{
    int4 hv = ((const int4*)hw)[lane];
    const int local = hv.x + hv.y + hv.z + hv.w;
    const int incl  = wave_incl_scan(local);
    if (allow_fail) {
        const int total = __builtin_amdgcn_readlane(incl, 63);
        if (total < KNB) return false;
    }
    const int excl = incl - local;
    const bool pred = (excl < KNB) && (incl >= KNB);
    const unsigned long long m = __ballot(pred);
    const int src = (m == 0ull) ? 0 : ((int)__ffsll(m) - 1);  // uniform
    int gg = 0, nnb = 0;
    if (pred) {
        const int hh[4] = {hv.x, hv.y, hv.z, hv.w};
        int cacc = excl, found = -1;
        #pragma unroll
        for (int q = 0; q < 4; ++q) {
            if (found < 0 && cacc + hh[q] >= KNB) { found = q; nnb = cacc; }
            cacc += hh[q];
        }
        gg = (lane << 2) + found;
    }
    const int g1  = __builtin_amdgcn_readlane(gg,  src);
    const int nb1 = __builtin_amdgcn_readlane(nnb, src);

    unsigned int bw[8];
    #pragma unroll
    for (int q = 0; q < 8; ++q) bw[q] = binsW[q][lane];

    unsigned int maskA = 0u, maskB = 0u;
    #pragma unroll
    for (int j = 0; j < 32; ++j) {
        const int bb = (int)((bw[j >> 2] >> ((j & 3) * 8)) & 255u);
        if (bb < g1) maskA |= (1u << j);
        else if (bb == g1) maskB |= (1u << j);
    }
    maskB &= nearmask;                     // drop far/self sentinels (bin 255)

    const int packed = __popc(maskA) | (__popc(maskB) << 16);
    const int incl2  = wave_incl_scan(packed);
    const int excl2  = incl2 - packed;
    int baseA = excl2 & 0xFFFF;            // region A: [0, nb1)
    int baseB = nb1 + (excl2 >> 16);       // region B: [nb1, 40), capped
    while (maskA) {                        // ascending j: identical dsts
        const int j = __ffs(maskA) - 1; maskA &= maskA - 1;
        cp[baseA++] = lane + (j << 6);
    }
    while (maskB && baseB < KNB) {
        const int j = __ffs(maskB) - 1; maskB &= maskB - 1;
        cp[baseB++] = lane + (j << 6);
    }
    return true;
}

// rebuild_fb: rare fallback (unchanged from R13, passing)
static __device__ __forceinline__ void rebuild_fb(
    const float4* __restrict__ cb4, const float cvx, const float cvy,
    const float cvz, const float cvw, const int jself,
    const int lself, int* __restrict__ hw, unsigned int (&binsW)[8][64],
    unsigned int& nearm, const int lane)
{
    const int4 izero = {0, 0, 0, 0};
    ((int4*)hw)[lane] = izero;
    nearm = 0u;
    #pragma unroll
    for (int q = 0; q < 8; ++q) {
        unsigned int wq = 0u;
        #pragma unroll
        for (int t = 0; t < 4; ++t) {
            const int j = q * 4 + t;       // compile-time constant
            const float4 cw = cb4[lane + (j << 6)];
            const float dx = cvx - cw.x, dy = cvy - cw.y;
            const float dz = cvz - cw.z, dw = cvw - cw.w;
            float d2 = dx*dx + dy*dy + dz*dz + dw*dw;
            if (j == jself && lane == lself) d2 = FLT_MAX;
            const bool nr = (d2 < 1024.f);
            const int  bb = nr ? (int)(d2 * 0.25f) : 255;
            wq    |= (unsigned int)bb << (t * 8);
            nearm |= (nr ? 1u : 0u) << j;
            if (nr) atomicAdd(&hw[bb], 1);
        }
        binsW[q][lane] = wq;               // conflict-free ds_write_b32
        __builtin_amdgcn_sched_barrier(0); // cap in-flight loads
    }
}

// ---------------------------------------------------------------------------
// Kernel 2: k_knn — FUSED select + pool, TWO rows per wave.
// (unchanged from R13, passing: 155.7us, VGPR 40, no spill, VALUBusy 98%)
// ---------------------------------------------------------------------------
__global__ __launch_bounds__(256) void k_knn(
    const float* __restrict__ coords, const float* __restrict__ feats,
    float* __restrict__ collected)
{
    __shared__ int hist[4][2][256];              // 8 KB (per-wave x 2 rows)
    __shared__ int candP[4][2][KNB];             // 1.25 KB: neighbor idx
    __shared__ unsigned int binsT[4][2][8][64];  // 16 KB: transposed bins

    const int tid   = threadIdx.x;
    const int lane  = tid & 63;
    const int w     = tid >> 6;
    const int bid   = (int)blockIdx.x;
    const int swz   = ((bid & 7) << 10) + (bid >> 3);
    const int vA    = __builtin_amdgcn_readfirstlane((swz << 3) + (w << 1));
    const int batch = vA >> 11;
    const int vlocA = vA & (VV - 1);
    const float4* cb4 = (const float4*)(coords + (size_t)batch * VV * DD);
    const float*  fb  = feats + (size_t)batch * VV * PP;

    const int4 izero = {0, 0, 0, 0};

    const float4 cva = cb4[vlocA];
    const float4 cvb = cb4[vlocA + 1];
    const float cax = rfl_f(cva.x), cay = rfl_f(cva.y);
    const float caz = rfl_f(cva.z), caw = rfl_f(cva.w);
    const float cbx = rfl_f(cvb.x), cby = rfl_f(cvb.y);
    const float cbz = rfl_f(cvb.z), cbw = rfl_f(cvb.w);
    const int jself  = vlocA >> 6;
    const int lselfA = vlocA & 63;
    const int lselfB = lselfA + 1;

    ((int4*)hist[w][0])[lane] = izero;
    ((int4*)hist[w][1])[lane] = izero;

    unsigned int nearA = 0u, nearB = 0u;
    #pragma unroll
    for (int q = 0; q < 8; ++q) {
        unsigned int wqA = 0u, wqB = 0u;
        #pragma unroll
        for (int t = 0; t < 4; ++t) {
            const int j = q * 4 + t;
            const float4 cw = cb4[lane + (j << 6)];
            const float dxA = cax - cw.x, dyA = cay - cw.y;
            const float dzA = caz - cw.z, dwA = caw - cw.w;
            float d2A = dxA*dxA + dyA*dyA + dzA*dzA + dwA*dwA;
            const float dxB = cbx - cw.x, dyB = cby - cw.y;
            const float dzB = cbz - cw.z, dwB = cbw - cw.w;
            float d2B = dxB*dxB + dyB*dyB + dzB*dzB + dwB*dwB;
            if (j == jself) {
                if (lane == lselfA) d2A = FLT_MAX;
                if (lane == lselfB) d2B = FLT_MAX;
            }
            const bool nA = (d2A < 4.f), nB = (d2B < 4.f);
            const int  bA = nA ? (int)(d2A * 64.f) : 255;
            const int  bB = nB ? (int)(d2B * 64.f) : 255;
            wqA   |= (unsigned int)bA << (t * 8);
            wqB   |= (unsigned int)bB << (t * 8);
            nearA |= (nA ? 1u : 0u) << j;
            nearB |= (nB ? 1u : 0u) << j;
            if (nA) atomicAdd(&hist[w][0][bA], 1);
            if (nB) atomicAdd(&hist[w][1][bB], 1);
        }
        binsT[w][0][q][lane] = wqA;
        binsT[w][1][q][lane] = wqB;
        __builtin_amdgcn_sched_barrier(0);
    }

    if (!select_collect(binsT[w][0], nearA, hist[w][0], candP[w][0], lane, true)) {
        rebuild_fb(cb4, cax, cay, caz, caw, jself, lselfA,
                   hist[w][0], binsT[w][0], nearA, lane);
        select_collect(binsT[w][0], nearA, hist[w][0], candP[w][0], lane, false);
    }
    if (!select_collect(binsT[w][1], nearB, hist[w][1], candP[w][1], lane, true)) {
        rebuild_fb(cb4, cbx, cby, cbz, cbw, jself, lselfB,
                   hist[w][1], binsT[w][1], nearB, lane);
        select_collect(binsT[w][1], nearB, hist[w][1], candP[w][1], lane, false);
    }

    #pragma unroll
    for (int r = 0; r < 2; ++r) {
        const float qx = r ? cbx : cax, qy = r ? cby : cay;
        const float qz = r ? cbz : caz, qw = r ? cbw : caw;
        int ireg = 0; float wgt = 0.f;
        if (lane < KNB) {
            ireg = candP[w][r][lane];
            const float4 cw = cb4[ireg];
            const float dx = qx - cw.x, dy = qy - cw.y;
            const float dz = qz - cw.z, dw = qw - cw.w;
            wgt = __expf(-10.f * (dx*dx + dy*dy + dz*dz + dw*dw));
        }
        float mx = -FLT_MAX, sm = 0.f;
        #pragma unroll
        for (int j0 = 0; j0 < KNB; j0 += 20) {
            float fv[20]; float wv[20];
            #pragma unroll
            for (int t = 0; t < 20; ++t) {
                const int si = __builtin_amdgcn_readlane(ireg, j0 + t);   // SGPR
                wv[t] = __uint_as_float(
                    (unsigned int)__builtin_amdgcn_readlane(__float_as_int(wgt), j0 + t));
                fv[t] = fb[(size_t)(si * PP) + lane];                     // saddr
            }
            #pragma unroll
            for (int t = 0; t < 20; ++t) {
                const float nv = fv[t] * wv[t];
                mx = fmaxf(mx, nv);
                sm += nv;
            }
        }
        float* rowp = collected + ((size_t)(vA + r) << 7);
        rowp[lane]      = mx;
        rowp[PP + lane] = sm * (1.f / KNB);
    }
}

// ---------------------------------------------------------------------------
// Kernel 3: k_out = tanh(concat(x, collected) @ W_out + b_out) via bf16 MFMA.
// R14: k_out's fp32 vector-GEMM floor is 20.5us (3.2 GFLOP @ 157 TF) and its
// actual time is hidden inside the ~129us non-knn budget. bf16 MFMA runs at
// 2382 TF -> compute collapses toward the ~13us memory floor.
// LAYOUT-AGNOSTIC CONSTRUCTION: fill A-slot (lane,i) with A[row][q(lane,i)]
// and B-slot (lane,i) with B[q(lane,i)][col], q=(lane>>4)*8+i. Since MFMA
// contracts over ALL K slots and A/B share the slot->k map on CDNA, any
// shared bijection q is correct regardless of the HW's internal k order.
// D layout used: col=lane&15, row=(lane>>4)*4+reg [HW-verified m89/m91].
// W staged frag-major bf16 in LDS (48KB; B-frag = one conflict-free
// ds_read_b128). A-frags straight from global (lane-groups cover whole
// 128B lines), RNE-converted in registers. 8 waves x 16-row tiles = 128
// rows/block; 48 MFMA/wave. Accuracy: bf16 RNE on A,W; fp32 accum ->
// est. +6e-3 absmax (threshold 0.02; current 0.0039).
// ---------------------------------------------------------------------------
__global__ __launch_bounds__(512) void k_out(
    const float* __restrict__ x, const float* __restrict__ collected,
    const float* __restrict__ Wout, const float* __restrict__ bout,
    float* __restrict__ out)
{
    // Wf[ks][ct][lane] = 8 bf16 (16B): W[ks*32+(lane>>4)*8 + 0..7][ct*16+(lane&15)]
    __shared__ __align__(16) unsigned short Wf[6 * 8 * 64 * 8];   // 48 KB

    const int tid  = threadIdx.x;
    const int lane = tid & 63;
    const int wv   = tid >> 6;             // 0..7
    const int row0 = (int)blockIdx.x * 128;

    // ---- stage W frag-major: 3072 slots / 512 threads = 6 each ----
    for (int s = tid; s < 3072; s += 512) {
        const int l     = s & 63;
        const int ct    = (s >> 6) & 7;
        const int ks    = s >> 9;                  // 0..5
        const int kbase = ks * 32 + (l >> 4) * 8;
        const int col   = ct * 16 + (l & 15);
        unsigned int pk[4];
        #pragma unroll
        for (int p = 0; p < 4; ++p) {
            const float f0 = Wout[(size_t)(kbase + 2*p)     * 128 + col];
            const float f1 = Wout[(size_t)(kbase + 2*p + 1) * 128 + col];
            pk[p] = bf16rne(f0) | (bf16rne(f1) << 16);
        }
        uint4 v = {pk[0], pk[1], pk[2], pk[3]};
        *(uint4*)&Wf[s * 8] = v;
    }
    __syncthreads();

    // ---- per-wave 16x128 output tile, K=192 in 6 steps of 32 ----
    const int arow = row0 + wv * 16 + (lane & 15);     // A row for this lane
    const int koff = (lane >> 4) * 8;                  // q(lane,i) base
    f32x4 acc[8];
    #pragma unroll
    for (int ct = 0; ct < 8; ++ct) acc[ct] = (f32x4){0.f, 0.f, 0.f, 0.f};

    #pragma unroll
    for (int ks = 0; ks < 6; ++ks) {
        const float* src = (ks < 2)
            ? (x         + (size_t)arow * FIN + ks * 32 + koff)
            : (collected + (size_t)arow * 128 + (ks - 2) * 32 + koff);
        const float4 a0 = *(const float4*)(src);
        const float4 a1 = *(const float4*)(src + 4);
        unsigned int p0 = bf16rne(a0.x) | (bf16rne(a0.y) << 16);
        unsigned int p1 = bf16rne(a0.z) | (bf16rne(a0.w) << 16);
        unsigned int p2 = bf16rne(a1.x) | (bf16rne(a1.y) << 16);
        unsigned int p3 = bf16rne(a1.z) | (bf16rne(a1.w) << 16);
        uint4 av = {p0, p1, p2, p3};
        const bf16x8 afrag = *(const bf16x8*)&av;
        #pragma unroll
        for (int ct = 0; ct < 8; ++ct) {
            const bf16x8 bfrag = *(const bf16x8*)&Wf[((ks * 8 + ct) * 64 + lane) * 8];
            acc[ct] = __builtin_amdgcn_mfma_f32_16x16x32_bf16(
                          afrag, bfrag, acc[ct], 0, 0, 0);
        }
    }

    // ---- epilogue: D col=lane&15, row=(lane>>4)*4+reg [verified] ----
    const int orow0 = row0 + wv * 16 + (lane >> 4) * 4;
    #pragma unroll
    for (int ct = 0; ct < 8; ++ct) {
        const int ocol = ct * 16 + (lane & 15);
        const float bb = bout[ocol];
        #pragma unroll
        for (int i = 0; i < 4; ++i)
            out[(size_t)(orow0 + i) * 128 + ocol] = fast_tanh(acc[ct][i] + bb);
    }
}

// ---------------------------------------------------------------------------
extern "C" void kernel_launch(void* const* d_in, const int* in_sizes, int n_in,
                              void* d_out, int out_size, void* d_ws, size_t ws_size,
                              hipStream_t stream)
{
    const float* x    = (const float*)d_in[0];
    // d_in[1] = row_splits: uniform arange(B+1)*V — fixed structure, unused.
    const float* Ws   = (const float*)d_in[2];
    const float* bs   = (const float*)d_in[3];
    const float* Wf   = (const float*)d_in[4];
    const float* bf   = (const float*)d_in[5];
    const float* Wout = (const float*)d_in[6];
    const float* bout = (const float*)d_in[7];
    float* out = (float*)d_out;

    float* coords = (float*)d_ws;                                            // 1 MB
    float* feats  = (float*)((char*)d_ws + (size_t)NN * DD * sizeof(float)); // 16 MB
    float* collected = out;   // reuse d_out as scratch for pooled features

    hipLaunchKernelGGL(k_embed, dim3(NN / 64), dim3(256), 0, stream,
                       x, Ws, bs, Wf, bf, coords, feats);
    // fused select+pool: 2 rows per wave, 4 waves/block -> 8192 blocks
    hipLaunchKernelGGL(k_knn, dim3(NN / 8), dim3(256), 0, stream,
                       coords, feats, collected);
    // MFMA k_out: 128 rows/block (8 waves x 16) -> 512 blocks
    hipLaunchKernelGGL(k_out, dim3(NN / 128), dim3(512), 0, stream,
                       x, collected, Wout, bout, out);
}